// Round 2
// baseline (624.274 us; speedup 1.0000x reference)
//
#include <hip/hip_runtime.h>
#include <math.h>

typedef __attribute__((ext_vector_type(8))) __bf16 bf16x8;
typedef __attribute__((ext_vector_type(4))) float f32x4;

#define NBATCH 8
#define SEQ    1024
#define NHEAD  16
#define DHEAD  64
#define HID    1024
#define MLPD   4096

static __device__ __forceinline__ unsigned short f2bf(float f) {
  unsigned int u = __float_as_uint(f);
  u += 0x7fffu + ((u >> 16) & 1u);
  return (unsigned short)(u >> 16);
}

// ---------- transpose: in f32 (R x C) -> out bf16 (C x R) ----------
__global__ __launch_bounds__(256) void k_transpose(const float* __restrict__ in,
                                                   unsigned short* __restrict__ out,
                                                   int R, int C) {
  __shared__ float t[32][33];
  const int tx = threadIdx.x & 31, ty = threadIdx.x >> 5;  // 32 x 8
  const int c0 = blockIdx.x * 32, r0 = blockIdx.y * 32;
#pragma unroll
  for (int j = 0; j < 4; ++j)
    t[ty + j * 8][tx] = in[(size_t)(r0 + ty + j * 8) * C + c0 + tx];
  __syncthreads();
#pragma unroll
  for (int j = 0; j < 4; ++j)
    out[(size_t)(c0 + ty + j * 8) * R + r0 + tx] = f2bf(t[tx][ty + j * 8]);
}

// ---------- pack q/k/v biases into one 3072 vector ----------
__global__ void k_pack_bias(const float* __restrict__ bq, const float* __restrict__ bk,
                            const float* __restrict__ bv, float* __restrict__ o) {
  int i = blockIdx.x * 256 + threadIdx.x;
  if (i < 3 * HID) {
    float v = (i < HID) ? bq[i] : (i < 2 * HID ? bk[i - HID] : bv[i - 2 * HID]);
    o[i] = v;
  }
}

// ---------- layernorm: f32 row (1024) -> bf16 row ----------
__global__ __launch_bounds__(256) void k_ln(const float* __restrict__ x,
                                            const float* __restrict__ gw,
                                            const float* __restrict__ bw,
                                            unsigned short* __restrict__ y) {
  __shared__ float red[2][4];
  const int row = blockIdx.x;
  const int tid = threadIdx.x;
  const float4 v = ((const float4*)(x + (size_t)row * HID))[tid];
  float sum = v.x + v.y + v.z + v.w;
  float sq  = v.x * v.x + v.y * v.y + v.z * v.z + v.w * v.w;
#pragma unroll
  for (int off = 32; off >= 1; off >>= 1) {
    sum += __shfl_xor(sum, off);
    sq  += __shfl_xor(sq, off);
  }
  if ((tid & 63) == 0) { red[0][tid >> 6] = sum; red[1][tid >> 6] = sq; }
  __syncthreads();
  sum = red[0][0] + red[0][1] + red[0][2] + red[0][3];
  sq  = red[1][0] + red[1][1] + red[1][2] + red[1][3];
  const float mu  = sum * (1.0f / HID);
  const float var = sq * (1.0f / HID) - mu * mu;
  const float rs  = rsqrtf(var + 1e-5f);
  const float4 g4 = ((const float4*)gw)[tid];
  const float4 b4 = ((const float4*)bw)[tid];
  ushort4 ov;
  ov.x = f2bf((v.x - mu) * rs * g4.x + b4.x);
  ov.y = f2bf((v.y - mu) * rs * g4.y + b4.y);
  ov.z = f2bf((v.z - mu) * rs * g4.z + b4.z);
  ov.w = f2bf((v.w - mu) * rs * g4.w + b4.w);
  ((ushort4*)(y + (size_t)row * HID))[tid] = ov;
}

// ---------- NT GEMM: C(MxN) = A(MxK) * BT(NxK)^T, bf16 in, f32 acc ----------
template <int EPI>
__global__ __launch_bounds__(256) void k_gemm(const unsigned short* __restrict__ A,
                                              const unsigned short* __restrict__ BT,
                                              const float* __restrict__ bias,
                                              const float* __restrict__ res,
                                              void* __restrict__ Cout,
                                              int M, int N, int K) {
  __shared__ unsigned short As[128 * 40];
  __shared__ unsigned short Bs[128 * 40];
  const int tid  = threadIdx.x;
  const int lane = tid & 63;
  const int w    = tid >> 6;
  const int wr   = w >> 1, wc = w & 1;
  const int l15  = lane & 15, g = lane >> 4;
  const int m0 = blockIdx.y * 128, n0 = blockIdx.x * 128;

  f32x4 acc[4][4] = {};

  const int srow = tid >> 2;        // 0..63
  const int scol = (tid & 3) * 8;   // 0,8,16,24

  for (int k0 = 0; k0 < K; k0 += 32) {
    __syncthreads();
#pragma unroll
    for (int c = 0; c < 2; ++c) {
      int row = srow + c * 64;
      *(uint4*)(&As[row * 40 + scol]) =
          *(const uint4*)(&A[(size_t)(m0 + row) * K + k0 + scol]);
      *(uint4*)(&Bs[row * 40 + scol]) =
          *(const uint4*)(&BT[(size_t)(n0 + row) * K + k0 + scol]);
    }
    __syncthreads();
    bf16x8 af[4], bfr[4];
#pragma unroll
    for (int m = 0; m < 4; ++m)
      af[m] = *(const bf16x8*)(&As[(wr * 64 + m * 16 + l15) * 40 + g * 8]);
#pragma unroll
    for (int n = 0; n < 4; ++n)
      bfr[n] = *(const bf16x8*)(&Bs[(wc * 64 + n * 16 + l15) * 40 + g * 8]);
#pragma unroll
    for (int m = 0; m < 4; ++m)
#pragma unroll
      for (int n = 0; n < 4; ++n)
        acc[m][n] = __builtin_amdgcn_mfma_f32_16x16x32_bf16(af[m], bfr[n], acc[m][n], 0, 0, 0);
  }

#pragma unroll
  for (int m = 0; m < 4; ++m) {
#pragma unroll
    for (int n = 0; n < 4; ++n) {
      const int col = n0 + wc * 64 + n * 16 + l15;
      const float bc = bias[col];
#pragma unroll
      for (int r = 0; r < 4; ++r) {
        const int row = m0 + wr * 64 + m * 16 + g * 4 + r;
        const size_t idx = (size_t)row * N + col;
        float v = acc[m][n][r] + bc;
        if constexpr (EPI == 0) {
          ((unsigned short*)Cout)[idx] = f2bf(v);
        } else if constexpr (EPI == 1) {
          float tv = tanhf(0.7978845608028654f * (v + 0.044715f * v * v * v));
          ((unsigned short*)Cout)[idx] = f2bf(0.5f * v * (1.0f + tv));
        } else {
          ((float*)Cout)[idx] = v + res[idx];
        }
      }
    }
  }
}

// ---------- V transpose: qkv (M x 3072) V-columns -> vT [nh][64][1024] bf16 ----------
__global__ __launch_bounds__(256) void k_vt(const unsigned short* __restrict__ qkv,
                                            unsigned short* __restrict__ vT) {
  __shared__ unsigned short t[64][72];
  const int nh = blockIdx.y;           // nb*16 + h
  const int nb = nh >> 4, h = nh & 15;
  const int l0 = blockIdx.x * 64;
  const int tx = threadIdx.x & 7;      // 8 chunks of 8 d-elems
  const int ty = threadIdx.x >> 3;     // 32 l-rows
  const unsigned short* src = qkv + (size_t)(nb * SEQ + l0) * 3072 + 2048 + h * DHEAD;
#pragma unroll
  for (int j = 0; j < 2; ++j)
    *(uint4*)(&t[ty + j * 32][tx * 8]) =
        *(const uint4*)(&src[(size_t)(ty + j * 32) * 3072 + tx * 8]);
  __syncthreads();
  unsigned short* dst = vT + (size_t)nh * DHEAD * SEQ + l0;
#pragma unroll
  for (int j = 0; j < 2; ++j) {
    const int d = ty + j * 32;
    ushort4 a, b;
    a.x = t[tx * 8 + 0][d]; a.y = t[tx * 8 + 1][d];
    a.z = t[tx * 8 + 2][d]; a.w = t[tx * 8 + 3][d];
    b.x = t[tx * 8 + 4][d]; b.y = t[tx * 8 + 5][d];
    b.z = t[tx * 8 + 6][d]; b.w = t[tx * 8 + 7][d];
    *(ushort4*)(&dst[(size_t)d * SEQ + tx * 8])     = a;
    *(ushort4*)(&dst[(size_t)d * SEQ + tx * 8 + 4]) = b;
  }
}

// ---------- flash attention: Q,K from qkv; V^T coalesced; KBLK=64 ----------
__global__ __launch_bounds__(256) void k_attn(const unsigned short* __restrict__ qkv,
                                              const unsigned short* __restrict__ vT,
                                              unsigned short* __restrict__ outp) {
  __shared__ unsigned short P_lds[4][16 * 72];
  const int tid  = threadIdx.x;
  const int lane = tid & 63;
  const int w    = tid >> 6;
  const int l15  = lane & 15, g = lane >> 4;
  const int nh = blockIdx.y;
  const int nb = nh >> 4, h = nh & 15;
  const int qbase = blockIdx.x * 64 + w * 16;
  const size_t RS = 3 * HID;

  const unsigned short* Qp = qkv + (size_t)(nb * SEQ + qbase) * RS + h * DHEAD;
  const unsigned short* Kp = qkv + (size_t)(nb * SEQ) * RS + HID + h * DHEAD;
  const unsigned short* Vt = vT + (size_t)nh * DHEAD * SEQ;

  bf16x8 aq[2];
#pragma unroll
  for (int t = 0; t < 2; ++t)
    aq[t] = *(const bf16x8*)(&Qp[(size_t)l15 * RS + t * 32 + g * 8]);

  f32x4 o[4] = {};
  float mrow[4], srow[4];
#pragma unroll
  for (int r = 0; r < 4; ++r) { mrow[r] = -INFINITY; srow[r] = 0.0f; }

  for (int kb = 0; kb < SEQ; kb += 64) {
    f32x4 S[4];
#pragma unroll
    for (int c = 0; c < 4; ++c) {
      f32x4 sa = {};
#pragma unroll
      for (int t = 0; t < 2; ++t) {
        bf16x8 bk = *(const bf16x8*)(&Kp[(size_t)(kb + c * 16 + l15) * RS + t * 32 + g * 8]);
        sa = __builtin_amdgcn_mfma_f32_16x16x32_bf16(aq[t], bk, sa, 0, 0, 0);
      }
      S[c] = sa;
    }
#pragma unroll
    for (int r = 0; r < 4; ++r) {
      float s0 = S[0][r] * 0.125f, s1 = S[1][r] * 0.125f;
      float s2 = S[2][r] * 0.125f, s3 = S[3][r] * 0.125f;
      float tmax = fmaxf(fmaxf(s0, s1), fmaxf(s2, s3));
#pragma unroll
      for (int off = 8; off >= 1; off >>= 1)
        tmax = fmaxf(tmax, __shfl_xor(tmax, off));
      const float mnew = fmaxf(mrow[r], tmax);
      const float sc = __expf(mrow[r] - mnew);
      mrow[r] = mnew;
      const float p0 = __expf(s0 - mnew), p1 = __expf(s1 - mnew);
      const float p2 = __expf(s2 - mnew), p3 = __expf(s3 - mnew);
      const int prow = (g * 4 + r) * 72;
      P_lds[w][prow + l15]      = f2bf(p0);
      P_lds[w][prow + 16 + l15] = f2bf(p1);
      P_lds[w][prow + 32 + l15] = f2bf(p2);
      P_lds[w][prow + 48 + l15] = f2bf(p3);
      float ts = (p0 + p1) + (p2 + p3);
#pragma unroll
      for (int off = 8; off >= 1; off >>= 1)
        ts += __shfl_xor(ts, off);
      srow[r] = srow[r] * sc + ts;
#pragma unroll
      for (int dt = 0; dt < 4; ++dt) o[dt][r] *= sc;
    }
    const bf16x8 pa0 = *(const bf16x8*)(&P_lds[w][l15 * 72 + g * 8]);
    const bf16x8 pa1 = *(const bf16x8*)(&P_lds[w][l15 * 72 + 32 + g * 8]);
#pragma unroll
    for (int dt = 0; dt < 4; ++dt) {
      const bf16x8 v0 = *(const bf16x8*)(&Vt[(size_t)(dt * 16 + l15) * SEQ + kb + g * 8]);
      const bf16x8 v1 = *(const bf16x8*)(&Vt[(size_t)(dt * 16 + l15) * SEQ + kb + 32 + g * 8]);
      o[dt] = __builtin_amdgcn_mfma_f32_16x16x32_bf16(pa0, v0, o[dt], 0, 0, 0);
      o[dt] = __builtin_amdgcn_mfma_f32_16x16x32_bf16(pa1, v1, o[dt], 0, 0, 0);
    }
  }
#pragma unroll
  for (int dt = 0; dt < 4; ++dt)
#pragma unroll
    for (int r = 0; r < 4; ++r)
      outp[(size_t)(nb * SEQ + qbase + g * 4 + r) * HID + h * DHEAD + dt * 16 + l15] =
          f2bf(o[dt][r] / srow[r]);
}

extern "C" void kernel_launch(void* const* d_in, const int* in_sizes, int n_in,
                              void* d_out, int out_size, void* d_ws, size_t ws_size,
                              hipStream_t stream) {
  const float* x    = (const float*)d_in[0];
  const float* ln0g = (const float*)d_in[1];
  const float* ln0b = (const float*)d_in[2];
  const float* wq   = (const float*)d_in[3];
  const float* bq   = (const float*)d_in[4];
  const float* wk   = (const float*)d_in[5];
  const float* bk   = (const float*)d_in[6];
  const float* wv   = (const float*)d_in[7];
  const float* bv   = (const float*)d_in[8];
  const float* wo   = (const float*)d_in[9];
  const float* bo   = (const float*)d_in[10];
  const float* ln1g = (const float*)d_in[11];
  const float* ln1b = (const float*)d_in[12];
  const float* w1   = (const float*)d_in[13];
  const float* b1   = (const float*)d_in[14];
  const float* w2   = (const float*)d_in[15];
  const float* b2   = (const float*)d_in[16];
  float* out = (float*)d_out;

  char* ws = (char*)d_ws;
  // workspace layout (bytes)
  unsigned short* qkvT = (unsigned short*)(ws + 0);          // 3072x1024 bf16   (6 MB)
  unsigned short* woT  = (unsigned short*)(ws + 6291456);    // 1024x1024 bf16   (2 MB)
  unsigned short* w1T  = (unsigned short*)(ws + 8388608);    // 4096x1024 bf16   (8 MB)
  unsigned short* w2T  = (unsigned short*)(ws + 16777216);   // 1024x4096 bf16   (8 MB)
  float*          bqkv = (float*)(ws + 25165824);            // 3072 f32
  unsigned short* ybuf = (unsigned short*)(ws + 25178112);   // 8192x1024 bf16   (16 MB)
  unsigned short* qkv  = (unsigned short*)(ws + 41955328);   // 8192x3072 bf16   (48 MB)
  unsigned short* att  = (unsigned short*)(ws + 92286976);   // 8192x1024 bf16   (16 MB)
  unsigned short* hbuf = qkv;   // 8192x4096 bf16 (64 MB) overlays qkv+att (both dead)
  unsigned short* vT   = ybuf;  // 128x64x1024 bf16 (16 MB) overlays ybuf (dead between QKV-GEMM and LN1)

  const int M = NBATCH * SEQ;  // 8192

  // weight prep
  k_transpose<<<dim3(32, 32),  256, 0, stream>>>(wq, qkvT,                        HID,  HID);
  k_transpose<<<dim3(32, 32),  256, 0, stream>>>(wk, qkvT + (size_t)1024 * HID,   HID,  HID);
  k_transpose<<<dim3(32, 32),  256, 0, stream>>>(wv, qkvT + (size_t)2048 * HID,   HID,  HID);
  k_transpose<<<dim3(32, 32),  256, 0, stream>>>(wo, woT,                         HID,  HID);
  k_transpose<<<dim3(128, 32), 256, 0, stream>>>(w1, w1T,                         HID,  MLPD);
  k_transpose<<<dim3(32, 128), 256, 0, stream>>>(w2, w2T,                         MLPD, HID);
  k_pack_bias<<<dim3(12), 256, 0, stream>>>(bq, bk, bv, bqkv);

  // LN0 -> y
  k_ln<<<dim3(M), 256, 0, stream>>>(x, ln0g, ln0b, ybuf);
  // QKV: qkv = y @ [wq|wk|wv] + b   (M x 3072)
  k_gemm<0><<<dim3(24, 64), 256, 0, stream>>>(ybuf, qkvT, bqkv, nullptr, (void*)qkv, M, 3 * HID, HID);
  // V^T materialization (ybuf is dead now)
  k_vt<<<dim3(16, 128), 256, 0, stream>>>(qkv, vT);
  // attention
  k_attn<<<dim3(16, 128), 256, 0, stream>>>(qkv, vT, att);
  // x1 = x + att @ wo + bo  -> d_out (f32)
  k_gemm<2><<<dim3(8, 64), 256, 0, stream>>>(att, woT, bo, x, (void*)out, M, HID, HID);
  // LN1 -> y
  k_ln<<<dim3(M), 256, 0, stream>>>(out, ln1g, ln1b, ybuf);
  // h = gelu(y @ w1 + b1)  (M x 4096)
  k_gemm<1><<<dim3(32, 64), 256, 0, stream>>>(ybuf, w1T, b1, nullptr, (void*)hbuf, M, MLPD, HID);
  // out = d_out + h @ w2 + b2
  k_gemm<2><<<dim3(8, 64), 256, 0, stream>>>(hbuf, w2T, b2, out, (void*)out, M, HID, MLPD);
}

// Round 3
// 622.940 us; speedup vs baseline: 1.0021x; 1.0021x over previous
//
#include <hip/hip_runtime.h>
#include <math.h>

typedef __attribute__((ext_vector_type(8))) __bf16 bf16x8;
typedef __attribute__((ext_vector_type(4))) float f32x4;

#define NBATCH 8
#define SEQ    1024
#define NHEAD  16
#define DHEAD  64
#define HID    1024
#define MLPD   4096

static __device__ __forceinline__ unsigned short f2bf(float f) {
  unsigned int u = __float_as_uint(f);
  u += 0x7fffu + ((u >> 16) & 1u);
  return (unsigned short)(u >> 16);
}

// ---------- transpose: in f32 (R x C) -> out bf16 (C x R) ----------
__global__ __launch_bounds__(256) void k_transpose(const float* __restrict__ in,
                                                   unsigned short* __restrict__ out,
                                                   int R, int C) {
  __shared__ float t[32][33];
  const int tx = threadIdx.x & 31, ty = threadIdx.x >> 5;  // 32 x 8
  const int c0 = blockIdx.x * 32, r0 = blockIdx.y * 32;
#pragma unroll
  for (int j = 0; j < 4; ++j)
    t[ty + j * 8][tx] = in[(size_t)(r0 + ty + j * 8) * C + c0 + tx];
  __syncthreads();
#pragma unroll
  for (int j = 0; j < 4; ++j)
    out[(size_t)(c0 + ty + j * 8) * R + r0 + tx] = f2bf(t[tx][ty + j * 8]);
}

// ---------- pack q/k/v biases into one 3072 vector ----------
__global__ void k_pack_bias(const float* __restrict__ bq, const float* __restrict__ bk,
                            const float* __restrict__ bv, float* __restrict__ o) {
  int i = blockIdx.x * 256 + threadIdx.x;
  if (i < 3 * HID) {
    float v = (i < HID) ? bq[i] : (i < 2 * HID ? bk[i - HID] : bv[i - 2 * HID]);
    o[i] = v;
  }
}

// ---------- layernorm: f32 row (1024) -> bf16 row ----------
__global__ __launch_bounds__(256) void k_ln(const float* __restrict__ x,
                                            const float* __restrict__ gw,
                                            const float* __restrict__ bw,
                                            unsigned short* __restrict__ y) {
  __shared__ float red[2][4];
  const int row = blockIdx.x;
  const int tid = threadIdx.x;
  const float4 v = ((const float4*)(x + (size_t)row * HID))[tid];
  float sum = v.x + v.y + v.z + v.w;
  float sq  = v.x * v.x + v.y * v.y + v.z * v.z + v.w * v.w;
#pragma unroll
  for (int off = 32; off >= 1; off >>= 1) {
    sum += __shfl_xor(sum, off);
    sq  += __shfl_xor(sq, off);
  }
  if ((tid & 63) == 0) { red[0][tid >> 6] = sum; red[1][tid >> 6] = sq; }
  __syncthreads();
  sum = red[0][0] + red[0][1] + red[0][2] + red[0][3];
  sq  = red[1][0] + red[1][1] + red[1][2] + red[1][3];
  const float mu  = sum * (1.0f / HID);
  const float var = sq * (1.0f / HID) - mu * mu;
  const float rs  = rsqrtf(var + 1e-5f);
  const float4 g4 = ((const float4*)gw)[tid];
  const float4 b4 = ((const float4*)bw)[tid];
  ushort4 ov;
  ov.x = f2bf((v.x - mu) * rs * g4.x + b4.x);
  ov.y = f2bf((v.y - mu) * rs * g4.y + b4.y);
  ov.z = f2bf((v.z - mu) * rs * g4.z + b4.z);
  ov.w = f2bf((v.w - mu) * rs * g4.w + b4.w);
  ((ushort4*)(y + (size_t)row * HID))[tid] = ov;
}

// ---------- NT GEMM: C(MxN) = A(MxK) * BT(NxK)^T, bf16 in, f32 acc ----------
template <int EPI>
__global__ __launch_bounds__(256) void k_gemm(const unsigned short* __restrict__ A,
                                              const unsigned short* __restrict__ BT,
                                              const float* __restrict__ bias,
                                              const float* __restrict__ res,
                                              void* __restrict__ Cout,
                                              int M, int N, int K) {
  __shared__ unsigned short As[128 * 40];
  __shared__ unsigned short Bs[128 * 40];
  const int tid  = threadIdx.x;
  const int lane = tid & 63;
  const int w    = tid >> 6;
  const int wr   = w >> 1, wc = w & 1;
  const int l15  = lane & 15, g = lane >> 4;
  const int m0 = blockIdx.y * 128, n0 = blockIdx.x * 128;

  f32x4 acc[4][4] = {};

  const int srow = tid >> 2;        // 0..63
  const int scol = (tid & 3) * 8;   // 0,8,16,24

  for (int k0 = 0; k0 < K; k0 += 32) {
    __syncthreads();
#pragma unroll
    for (int c = 0; c < 2; ++c) {
      int row = srow + c * 64;
      *(uint4*)(&As[row * 40 + scol]) =
          *(const uint4*)(&A[(size_t)(m0 + row) * K + k0 + scol]);
      *(uint4*)(&Bs[row * 40 + scol]) =
          *(const uint4*)(&BT[(size_t)(n0 + row) * K + k0 + scol]);
    }
    __syncthreads();
    bf16x8 af[4], bfr[4];
#pragma unroll
    for (int m = 0; m < 4; ++m)
      af[m] = *(const bf16x8*)(&As[(wr * 64 + m * 16 + l15) * 40 + g * 8]);
#pragma unroll
    for (int n = 0; n < 4; ++n)
      bfr[n] = *(const bf16x8*)(&Bs[(wc * 64 + n * 16 + l15) * 40 + g * 8]);
#pragma unroll
    for (int m = 0; m < 4; ++m)
#pragma unroll
      for (int n = 0; n < 4; ++n)
        acc[m][n] = __builtin_amdgcn_mfma_f32_16x16x32_bf16(af[m], bfr[n], acc[m][n], 0, 0, 0);
  }

#pragma unroll
  for (int m = 0; m < 4; ++m) {
#pragma unroll
    for (int n = 0; n < 4; ++n) {
      const int col = n0 + wc * 64 + n * 16 + l15;
      const float bc = bias[col];
#pragma unroll
      for (int r = 0; r < 4; ++r) {
        const int row = m0 + wr * 64 + m * 16 + g * 4 + r;
        const size_t idx = (size_t)row * N + col;
        float v = acc[m][n][r] + bc;
        if constexpr (EPI == 0) {
          ((unsigned short*)Cout)[idx] = f2bf(v);
        } else if constexpr (EPI == 1) {
          float tv = tanhf(0.7978845608028654f * (v + 0.044715f * v * v * v));
          ((unsigned short*)Cout)[idx] = f2bf(0.5f * v * (1.0f + tv));
        } else {
          ((float*)Cout)[idx] = v + res[idx];
        }
      }
    }
  }
}

// ---------- V transpose: qkv (M x 3072) V-columns -> vT [nh][64][1024] bf16 ----------
__global__ __launch_bounds__(256) void k_vt(const unsigned short* __restrict__ qkv,
                                            unsigned short* __restrict__ vT) {
  __shared__ unsigned short t[64][72];
  const int nh = blockIdx.y;           // nb*16 + h
  const int nb = nh >> 4, h = nh & 15;
  const int l0 = blockIdx.x * 64;
  const int tx = threadIdx.x & 7;      // 8 chunks of 8 d-elems
  const int ty = threadIdx.x >> 3;     // 32 l-rows
  const unsigned short* src = qkv + (size_t)(nb * SEQ + l0) * 3072 + 2048 + h * DHEAD;
#pragma unroll
  for (int j = 0; j < 2; ++j)
    *(uint4*)(&t[ty + j * 32][tx * 8]) =
        *(const uint4*)(&src[(size_t)(ty + j * 32) * 3072 + tx * 8]);
  __syncthreads();
  unsigned short* dst = vT + (size_t)nh * DHEAD * SEQ + l0;
#pragma unroll
  for (int j = 0; j < 2; ++j) {
    const int d = ty + j * 32;
    ushort4 a, b;
    a.x = t[tx * 8 + 0][d]; a.y = t[tx * 8 + 1][d];
    a.z = t[tx * 8 + 2][d]; a.w = t[tx * 8 + 3][d];
    b.x = t[tx * 8 + 4][d]; b.y = t[tx * 8 + 5][d];
    b.z = t[tx * 8 + 6][d]; b.w = t[tx * 8 + 7][d];
    *(ushort4*)(&dst[(size_t)d * SEQ + tx * 8])     = a;
    *(ushort4*)(&dst[(size_t)d * SEQ + tx * 8 + 4]) = b;
  }
}

// ---------- flash attention, swapped QK^T: lane-local softmax ----------
// S^T = mfma(K, Q): lane holds S[q = lane&15][k = kb + c*16 + (lane>>4)*4 + r]
__global__ __launch_bounds__(256) void k_attn(const unsigned short* __restrict__ qkv,
                                              const unsigned short* __restrict__ vT,
                                              unsigned short* __restrict__ outp) {
  __shared__ unsigned short P_lds[4][16 * 72];
  const int tid  = threadIdx.x;
  const int lane = tid & 63;
  const int w    = tid >> 6;
  const int l15  = lane & 15, g = lane >> 4;
  const int nh = blockIdx.y;
  const int nb = nh >> 4, h = nh & 15;
  const int qbase = blockIdx.x * 64 + w * 16;
  const size_t RS = 3 * HID;

  const unsigned short* Qp = qkv + (size_t)(nb * SEQ + qbase) * RS + h * DHEAD;
  const unsigned short* Kp = qkv + (size_t)(nb * SEQ) * RS + HID + h * DHEAD;
  const unsigned short* Vt = vT + (size_t)nh * DHEAD * SEQ;

  bf16x8 aq[2];
#pragma unroll
  for (int t = 0; t < 2; ++t)
    aq[t] = *(const bf16x8*)(&Qp[(size_t)l15 * RS + t * 32 + g * 8]);

  f32x4 o[4] = {};
  float m_run = -INFINITY;  // softmax state for q-row = l15
  float s_run = 0.0f;

  for (int kb = 0; kb < SEQ; kb += 64) {
    f32x4 S[4];
#pragma unroll
    for (int c = 0; c < 4; ++c) {
      f32x4 sa = {};
#pragma unroll
      for (int t = 0; t < 2; ++t) {
        bf16x8 bk = *(const bf16x8*)(&Kp[(size_t)(kb + c * 16 + l15) * RS + t * 32 + g * 8]);
        sa = __builtin_amdgcn_mfma_f32_16x16x32_bf16(bk, aq[t], sa, 0, 0, 0);
      }
      S[c] = sa;
    }
    // lane-local max over the 16 S-values (raw units), then 2-step cross-group reduce
    float mx = -INFINITY;
#pragma unroll
    for (int c = 0; c < 4; ++c)
#pragma unroll
      for (int r = 0; r < 4; ++r) mx = fmaxf(mx, S[c][r]);
    mx = fmaxf(mx, __shfl_xor(mx, 16));
    mx = fmaxf(mx, __shfl_xor(mx, 32));
    const float mnew = fmaxf(m_run, mx);
    const float sc = __expf(0.125f * (m_run - mnew));
    m_run = mnew;

    float ts = 0.0f;
#pragma unroll
    for (int c = 0; c < 4; ++c) {
      float p0 = __expf(0.125f * (S[c][0] - mnew));
      float p1 = __expf(0.125f * (S[c][1] - mnew));
      float p2 = __expf(0.125f * (S[c][2] - mnew));
      float p3 = __expf(0.125f * (S[c][3] - mnew));
      ts += (p0 + p1) + (p2 + p3);
      unsigned int lo = (unsigned int)f2bf(p0) | ((unsigned int)f2bf(p1) << 16);
      unsigned int hi = (unsigned int)f2bf(p2) | ((unsigned int)f2bf(p3) << 16);
      // P[q = l15][k = c*16 + g*4 + {0..3}], row stride 72 elems (144 B)
      *(uint2*)(&P_lds[w][l15 * 72 + c * 16 + g * 4]) = make_uint2(lo, hi);
    }
    ts += __shfl_xor(ts, 16);
    ts += __shfl_xor(ts, 32);
    s_run = s_run * sc + ts;

    // broadcast sc to the O-accumulator layout rows (q' = g*4 + r)
    float scr[4];
#pragma unroll
    for (int r = 0; r < 4; ++r) scr[r] = __shfl(sc, g * 4 + r);
#pragma unroll
    for (int dt = 0; dt < 4; ++dt)
#pragma unroll
      for (int r = 0; r < 4; ++r) o[dt][r] *= scr[r];

    const bf16x8 pa0 = *(const bf16x8*)(&P_lds[w][l15 * 72 + g * 8]);
    const bf16x8 pa1 = *(const bf16x8*)(&P_lds[w][l15 * 72 + 32 + g * 8]);
#pragma unroll
    for (int dt = 0; dt < 4; ++dt) {
      const bf16x8 v0 = *(const bf16x8*)(&Vt[(size_t)(dt * 16 + l15) * SEQ + kb + g * 8]);
      const bf16x8 v1 = *(const bf16x8*)(&Vt[(size_t)(dt * 16 + l15) * SEQ + kb + 32 + g * 8]);
      o[dt] = __builtin_amdgcn_mfma_f32_16x16x32_bf16(pa0, v0, o[dt], 0, 0, 0);
      o[dt] = __builtin_amdgcn_mfma_f32_16x16x32_bf16(pa1, v1, o[dt], 0, 0, 0);
    }
  }

  float sr[4];
#pragma unroll
  for (int r = 0; r < 4; ++r) sr[r] = __shfl(s_run, g * 4 + r);
#pragma unroll
  for (int dt = 0; dt < 4; ++dt)
#pragma unroll
    for (int r = 0; r < 4; ++r)
      outp[(size_t)(nb * SEQ + qbase + g * 4 + r) * HID + h * DHEAD + dt * 16 + l15] =
          f2bf(o[dt][r] / sr[r]);
}

extern "C" void kernel_launch(void* const* d_in, const int* in_sizes, int n_in,
                              void* d_out, int out_size, void* d_ws, size_t ws_size,
                              hipStream_t stream) {
  const float* x    = (const float*)d_in[0];
  const float* ln0g = (const float*)d_in[1];
  const float* ln0b = (const float*)d_in[2];
  const float* wq   = (const float*)d_in[3];
  const float* bq   = (const float*)d_in[4];
  const float* wk   = (const float*)d_in[5];
  const float* bk   = (const float*)d_in[6];
  const float* wv   = (const float*)d_in[7];
  const float* bv   = (const float*)d_in[8];
  const float* wo   = (const float*)d_in[9];
  const float* bo   = (const float*)d_in[10];
  const float* ln1g = (const float*)d_in[11];
  const float* ln1b = (const float*)d_in[12];
  const float* w1   = (const float*)d_in[13];
  const float* b1   = (const float*)d_in[14];
  const float* w2   = (const float*)d_in[15];
  const float* b2   = (const float*)d_in[16];
  float* out = (float*)d_out;

  char* ws = (char*)d_ws;
  // workspace layout (bytes)
  unsigned short* qkvT = (unsigned short*)(ws + 0);          // 3072x1024 bf16   (6 MB)
  unsigned short* woT  = (unsigned short*)(ws + 6291456);    // 1024x1024 bf16   (2 MB)
  unsigned short* w1T  = (unsigned short*)(ws + 8388608);    // 4096x1024 bf16   (8 MB)
  unsigned short* w2T  = (unsigned short*)(ws + 16777216);   // 1024x4096 bf16   (8 MB)
  float*          bqkv = (float*)(ws + 25165824);            // 3072 f32
  unsigned short* ybuf = (unsigned short*)(ws + 25178112);   // 8192x1024 bf16   (16 MB)
  unsigned short* qkv  = (unsigned short*)(ws + 41955328);   // 8192x3072 bf16   (48 MB)
  unsigned short* att  = (unsigned short*)(ws + 92286976);   // 8192x1024 bf16   (16 MB)
  unsigned short* hbuf = qkv;   // 8192x4096 bf16 (64 MB) overlays qkv+att (both dead)
  unsigned short* vT   = ybuf;  // 128x64x1024 bf16 (16 MB) overlays ybuf (dead between QKV-GEMM and LN1)

  const int M = NBATCH * SEQ;  // 8192

  // weight prep
  k_transpose<<<dim3(32, 32),  256, 0, stream>>>(wq, qkvT,                        HID,  HID);
  k_transpose<<<dim3(32, 32),  256, 0, stream>>>(wk, qkvT + (size_t)1024 * HID,   HID,  HID);
  k_transpose<<<dim3(32, 32),  256, 0, stream>>>(wv, qkvT + (size_t)2048 * HID,   HID,  HID);
  k_transpose<<<dim3(32, 32),  256, 0, stream>>>(wo, woT,                         HID,  HID);
  k_transpose<<<dim3(128, 32), 256, 0, stream>>>(w1, w1T,                         HID,  MLPD);
  k_transpose<<<dim3(32, 128), 256, 0, stream>>>(w2, w2T,                         MLPD, HID);
  k_pack_bias<<<dim3(12), 256, 0, stream>>>(bq, bk, bv, bqkv);

  // LN0 -> y
  k_ln<<<dim3(M), 256, 0, stream>>>(x, ln0g, ln0b, ybuf);
  // QKV: qkv = y @ [wq|wk|wv] + b   (M x 3072)
  k_gemm<0><<<dim3(24, 64), 256, 0, stream>>>(ybuf, qkvT, bqkv, nullptr, (void*)qkv, M, 3 * HID, HID);
  // V^T materialization (ybuf is dead now)
  k_vt<<<dim3(16, 128), 256, 0, stream>>>(qkv, vT);
  // attention
  k_attn<<<dim3(16, 128), 256, 0, stream>>>(qkv, vT, att);
  // x1 = x + att @ wo + bo  -> d_out (f32)
  k_gemm<2><<<dim3(8, 64), 256, 0, stream>>>(att, woT, bo, x, (void*)out, M, HID, HID);
  // LN1 -> y
  k_ln<<<dim3(M), 256, 0, stream>>>(out, ln1g, ln1b, ybuf);
  // h = gelu(y @ w1 + b1)  (M x 4096)
  k_gemm<1><<<dim3(32, 64), 256, 0, stream>>>(ybuf, w1T, b1, nullptr, (void*)hbuf, M, MLPD, HID);
  // out = d_out + h @ w2 + b2
  k_gemm<2><<<dim3(8, 64), 256, 0, stream>>>(hbuf, w2T, b2, out, (void*)out, M, HID, MLPD);
}

// Round 4
// 469.068 us; speedup vs baseline: 1.3309x; 1.3280x over previous
//
#include <hip/hip_runtime.h>
#include <math.h>

typedef __attribute__((ext_vector_type(8))) __bf16 bf16x8;
typedef __attribute__((ext_vector_type(4))) float f32x4;

#define NBATCH 8
#define SEQ    1024
#define NHEAD  16
#define DHEAD  64
#define HID    1024
#define MLPD   4096

static __device__ __forceinline__ unsigned short f2bf(float f) {
  unsigned int u = __float_as_uint(f);
  u += 0x7fffu + ((u >> 16) & 1u);
  return (unsigned short)(u >> 16);
}

// ---------- transpose: in f32 (R x C) -> out bf16 (C x R) ----------
__global__ __launch_bounds__(256) void k_transpose(const float* __restrict__ in,
                                                   unsigned short* __restrict__ out,
                                                   int R, int C) {
  __shared__ float t[32][33];
  const int tx = threadIdx.x & 31, ty = threadIdx.x >> 5;  // 32 x 8
  const int c0 = blockIdx.x * 32, r0 = blockIdx.y * 32;
#pragma unroll
  for (int j = 0; j < 4; ++j)
    t[ty + j * 8][tx] = in[(size_t)(r0 + ty + j * 8) * C + c0 + tx];
  __syncthreads();
#pragma unroll
  for (int j = 0; j < 4; ++j)
    out[(size_t)(c0 + ty + j * 8) * R + r0 + tx] = f2bf(t[tx][ty + j * 8]);
}

// ---------- pack q/k/v biases into one 3072 vector ----------
__global__ void k_pack_bias(const float* __restrict__ bq, const float* __restrict__ bk,
                            const float* __restrict__ bv, float* __restrict__ o) {
  int i = blockIdx.x * 256 + threadIdx.x;
  if (i < 3 * HID) {
    float v = (i < HID) ? bq[i] : (i < 2 * HID ? bk[i - HID] : bv[i - 2 * HID]);
    o[i] = v;
  }
}

// ---------- layernorm: f32 row (1024) -> bf16 row ----------
__global__ __launch_bounds__(256) void k_ln(const float* __restrict__ x,
                                            const float* __restrict__ gw,
                                            const float* __restrict__ bw,
                                            unsigned short* __restrict__ y) {
  __shared__ float red[2][4];
  const int row = blockIdx.x;
  const int tid = threadIdx.x;
  const float4 v = ((const float4*)(x + (size_t)row * HID))[tid];
  float sum = v.x + v.y + v.z + v.w;
  float sq  = v.x * v.x + v.y * v.y + v.z * v.z + v.w * v.w;
#pragma unroll
  for (int off = 32; off >= 1; off >>= 1) {
    sum += __shfl_xor(sum, off);
    sq  += __shfl_xor(sq, off);
  }
  if ((tid & 63) == 0) { red[0][tid >> 6] = sum; red[1][tid >> 6] = sq; }
  __syncthreads();
  sum = red[0][0] + red[0][1] + red[0][2] + red[0][3];
  sq  = red[1][0] + red[1][1] + red[1][2] + red[1][3];
  const float mu  = sum * (1.0f / HID);
  const float var = sq * (1.0f / HID) - mu * mu;
  const float rs  = rsqrtf(var + 1e-5f);
  const float4 g4 = ((const float4*)gw)[tid];
  const float4 b4 = ((const float4*)bw)[tid];
  ushort4 ov;
  ov.x = f2bf((v.x - mu) * rs * g4.x + b4.x);
  ov.y = f2bf((v.y - mu) * rs * g4.y + b4.y);
  ov.z = f2bf((v.z - mu) * rs * g4.z + b4.z);
  ov.w = f2bf((v.w - mu) * rs * g4.w + b4.w);
  ((ushort4*)(y + (size_t)row * HID))[tid] = ov;
}

// ---------- NT GEMM: C(MxN) = A(MxK) * BT(NxK)^T, bf16 in, f32 acc ----------
template <int EPI>
__global__ __launch_bounds__(256) void k_gemm(const unsigned short* __restrict__ A,
                                              const unsigned short* __restrict__ BT,
                                              const float* __restrict__ bias,
                                              const float* __restrict__ res,
                                              void* __restrict__ Cout,
                                              int M, int N, int K) {
  __shared__ unsigned short As[128 * 40];
  __shared__ unsigned short Bs[128 * 40];
  const int tid  = threadIdx.x;
  const int lane = tid & 63;
  const int w    = tid >> 6;
  const int wr   = w >> 1, wc = w & 1;
  const int l15  = lane & 15, g = lane >> 4;
  const int m0 = blockIdx.y * 128, n0 = blockIdx.x * 128;

  f32x4 acc[4][4] = {};

  const int srow = tid >> 2;        // 0..63
  const int scol = (tid & 3) * 8;   // 0,8,16,24

  for (int k0 = 0; k0 < K; k0 += 32) {
    __syncthreads();
#pragma unroll
    for (int c = 0; c < 2; ++c) {
      int row = srow + c * 64;
      *(uint4*)(&As[row * 40 + scol]) =
          *(const uint4*)(&A[(size_t)(m0 + row) * K + k0 + scol]);
      *(uint4*)(&Bs[row * 40 + scol]) =
          *(const uint4*)(&BT[(size_t)(n0 + row) * K + k0 + scol]);
    }
    __syncthreads();
    bf16x8 af[4], bfr[4];
#pragma unroll
    for (int m = 0; m < 4; ++m)
      af[m] = *(const bf16x8*)(&As[(wr * 64 + m * 16 + l15) * 40 + g * 8]);
#pragma unroll
    for (int n = 0; n < 4; ++n)
      bfr[n] = *(const bf16x8*)(&Bs[(wc * 64 + n * 16 + l15) * 40 + g * 8]);
#pragma unroll
    for (int m = 0; m < 4; ++m)
#pragma unroll
      for (int n = 0; n < 4; ++n)
        acc[m][n] = __builtin_amdgcn_mfma_f32_16x16x32_bf16(af[m], bfr[n], acc[m][n], 0, 0, 0);
  }

#pragma unroll
  for (int m = 0; m < 4; ++m) {
#pragma unroll
    for (int n = 0; n < 4; ++n) {
      const int col = n0 + wc * 64 + n * 16 + l15;
      const float bc = bias[col];
#pragma unroll
      for (int r = 0; r < 4; ++r) {
        const int row = m0 + wr * 64 + m * 16 + g * 4 + r;
        const size_t idx = (size_t)row * N + col;
        float v = acc[m][n][r] + bc;
        if constexpr (EPI == 0) {
          ((unsigned short*)Cout)[idx] = f2bf(v);
        } else if constexpr (EPI == 1) {
          float tv = tanhf(0.7978845608028654f * (v + 0.044715f * v * v * v));
          ((unsigned short*)Cout)[idx] = f2bf(0.5f * v * (1.0f + tv));
        } else {
          ((float*)Cout)[idx] = v + res[idx];
        }
      }
    }
  }
}

// ---------- V transpose: qkv (M x 3072) V-columns -> vT [nh][64][1024] bf16 ----------
__global__ __launch_bounds__(256) void k_vt(const unsigned short* __restrict__ qkv,
                                            unsigned short* __restrict__ vT) {
  __shared__ unsigned short t[64][72];
  const int nh = blockIdx.y;           // nb*16 + h
  const int nb = nh >> 4, h = nh & 15;
  const int l0 = blockIdx.x * 64;
  const int tx = threadIdx.x & 7;      // 8 chunks of 8 d-elems
  const int ty = threadIdx.x >> 3;     // 32 l-rows
  const unsigned short* src = qkv + (size_t)(nb * SEQ + l0) * 3072 + 2048 + h * DHEAD;
#pragma unroll
  for (int j = 0; j < 2; ++j)
    *(uint4*)(&t[ty + j * 32][tx * 8]) =
        *(const uint4*)(&src[(size_t)(ty + j * 32) * 3072 + tx * 8]);
  __syncthreads();
  unsigned short* dst = vT + (size_t)nh * DHEAD * SEQ + l0;
#pragma unroll
  for (int j = 0; j < 2; ++j) {
    const int d = ty + j * 32;
    ushort4 a, b;
    a.x = t[tx * 8 + 0][d]; a.y = t[tx * 8 + 1][d];
    a.z = t[tx * 8 + 2][d]; a.w = t[tx * 8 + 3][d];
    b.x = t[tx * 8 + 4][d]; b.y = t[tx * 8 + 5][d];
    b.z = t[tx * 8 + 6][d]; b.w = t[tx * 8 + 7][d];
    *(ushort4*)(&dst[(size_t)d * SEQ + tx * 8])     = a;
    *(ushort4*)(&dst[(size_t)d * SEQ + tx * 8 + 4]) = b;
  }
}

// ---------- flash attention, LDS-staged K/V, swapped QK^T ----------
// Block: 4 waves x 32 q-rows = 128 q-rows of one (batch,head).
// Per 64-k tile: K-tile [64k][64d], V^T-tile [64d][64k] staged via
// reg-split async (load next early, ds_write after barrier), XOR-swizzled.
#define SOFTMAX_GROUP(S, gq)                                                       \
  {                                                                                \
    float mx = -INFINITY;                                                          \
    _Pragma("unroll") for (int c = 0; c < 4; ++c)                                  \
      _Pragma("unroll") for (int r = 0; r < 4; ++r)                                \
        mx = fmaxf(mx, S[c][r]);                                                   \
    mx = fmaxf(mx, __shfl_xor(mx, 16));                                            \
    mx = fmaxf(mx, __shfl_xor(mx, 32));                                            \
    const float mnew = fmaxf(m_run[gq], mx);                                       \
    const float sc = __expf(0.125f * (m_run[gq] - mnew));                          \
    m_run[gq] = mnew;                                                              \
    float ts = 0.0f;                                                               \
    _Pragma("unroll") for (int c = 0; c < 4; ++c) {                                \
      const float p0 = __expf(0.125f * (S[c][0] - mnew));                          \
      const float p1 = __expf(0.125f * (S[c][1] - mnew));                          \
      const float p2 = __expf(0.125f * (S[c][2] - mnew));                          \
      const float p3 = __expf(0.125f * (S[c][3] - mnew));                          \
      ts += (p0 + p1) + (p2 + p3);                                                 \
      const unsigned int lo = (unsigned int)f2bf(p0) | ((unsigned int)f2bf(p1) << 16); \
      const unsigned int hi = (unsigned int)f2bf(p2) | ((unsigned int)f2bf(p3) << 16); \
      *(uint2*)(&P_lds[w][((gq) * 16 + l15) * 72 + c * 16 + g * 4]) = make_uint2(lo, hi); \
    }                                                                              \
    ts += __shfl_xor(ts, 16);                                                      \
    ts += __shfl_xor(ts, 32);                                                      \
    s_run[gq] = s_run[gq] * sc + ts;                                               \
    const float scr0 = __shfl(sc, g * 4 + 0), scr1 = __shfl(sc, g * 4 + 1);        \
    const float scr2 = __shfl(sc, g * 4 + 2), scr3 = __shfl(sc, g * 4 + 3);        \
    _Pragma("unroll") for (int dt = 0; dt < 4; ++dt) {                             \
      o[gq][dt][0] *= scr0; o[gq][dt][1] *= scr1;                                  \
      o[gq][dt][2] *= scr2; o[gq][dt][3] *= scr3;                                  \
    }                                                                              \
  }

__global__ __launch_bounds__(256, 4) void k_attn(const unsigned short* __restrict__ qkv,
                                                 const unsigned short* __restrict__ vT,
                                                 unsigned short* __restrict__ outp) {
  __shared__ unsigned short Ks[64 * 64];           // 8 KB, swizzled
  __shared__ unsigned short Vs[64 * 64];           // 8 KB, swizzled
  __shared__ unsigned short P_lds[4][32 * 72];     // 18 KB, per-wave P
  const int tid  = threadIdx.x;
  const int lane = tid & 63;
  const int w    = tid >> 6;
  const int l15  = lane & 15, g = lane >> 4;
  const int nh = blockIdx.y;
  const int nb = nh >> 4, h = nh & 15;
  const int q0 = blockIdx.x * 128 + w * 32;        // wave's 32 q-rows
  const size_t RS = 3 * HID;

  const unsigned short* Qp = qkv + (size_t)(nb * SEQ + q0) * RS + h * DHEAD;
  const unsigned short* Kg = qkv + (size_t)(nb * SEQ) * RS + HID + h * DHEAD;
  const unsigned short* Vg = vT + (size_t)nh * DHEAD * SEQ;

  // staging geometry: thread covers tile bytes [tid*32, tid*32+32) as 2x16B;
  // LDS dest linear; global source col pre-swizzled (XOR involution).
  const int L0 = tid * 32, L1 = L0 + 16;
  const int kr0 = L0 >> 7, kc0 = (L0 & 127) ^ ((kr0 & 7) << 4);
  const int kr1 = L1 >> 7, kc1 = (L1 & 127) ^ ((kr1 & 7) << 4);

  bf16x8 aq[2][2];
#pragma unroll
  for (int gq = 0; gq < 2; ++gq)
#pragma unroll
    for (int t = 0; t < 2; ++t)
      aq[gq][t] = *(const bf16x8*)(&Qp[(size_t)(gq * 16 + l15) * RS + t * 32 + g * 8]);

  f32x4 o[2][4] = {};
  float m_run[2] = {-INFINITY, -INFINITY};
  float s_run[2] = {0.0f, 0.0f};

  uint4 rk0, rk1, rv0, rv1;
  // prologue: stage tile 0
  rk0 = *(const uint4*)(Kg + (size_t)kr0 * RS + (kc0 >> 1));
  rk1 = *(const uint4*)(Kg + (size_t)kr1 * RS + (kc1 >> 1));
  rv0 = *(const uint4*)(Vg + (size_t)kr0 * SEQ + (kc0 >> 1));
  rv1 = *(const uint4*)(Vg + (size_t)kr1 * SEQ + (kc1 >> 1));
  *(uint4*)(&Ks[tid * 16])     = rk0;
  *(uint4*)(&Ks[tid * 16 + 8]) = rk1;
  *(uint4*)(&Vs[tid * 16])     = rv0;
  *(uint4*)(&Vs[tid * 16 + 8]) = rv1;
  __syncthreads();

  const int sw = (l15 & 7) << 4;  // byte-swizzle for fragment reads

  for (int t16 = 0; t16 < 16; ++t16) {
    // issue next tile's global loads early (latency hides under compute)
    if (t16 < 15) {
      const int kb = (t16 + 1) * 64;
      rk0 = *(const uint4*)(Kg + (size_t)(kb + kr0) * RS + (kc0 >> 1));
      rk1 = *(const uint4*)(Kg + (size_t)(kb + kr1) * RS + (kc1 >> 1));
      rv0 = *(const uint4*)(Vg + (size_t)kr0 * SEQ + kb + (kc0 >> 1));
      rv1 = *(const uint4*)(Vg + (size_t)kr1 * SEQ + kb + (kc1 >> 1));
    }

    // ---- QK^T (swapped): S^T = mfma(K, Q); K-frags shared by both q-groups ----
    f32x4 S0[4], S1[4];
#pragma unroll
    for (int c = 0; c < 4; ++c) {
      const int krow = c * 16 + l15;
      const bf16x8 k0 = *(const bf16x8*)(&Ks[krow * 64 + ((( 0 + g * 16) ^ sw) >> 1)]);
      const bf16x8 k1 = *(const bf16x8*)(&Ks[krow * 64 + (((64 + g * 16) ^ sw) >> 1)]);
      f32x4 a = {};
      a = __builtin_amdgcn_mfma_f32_16x16x32_bf16(k0, aq[0][0], a, 0, 0, 0);
      a = __builtin_amdgcn_mfma_f32_16x16x32_bf16(k1, aq[0][1], a, 0, 0, 0);
      S0[c] = a;
      f32x4 b = {};
      b = __builtin_amdgcn_mfma_f32_16x16x32_bf16(k0, aq[1][0], b, 0, 0, 0);
      b = __builtin_amdgcn_mfma_f32_16x16x32_bf16(k1, aq[1][1], b, 0, 0, 0);
      S1[c] = b;
    }

    SOFTMAX_GROUP(S0, 0)
    SOFTMAX_GROUP(S1, 1)

    // ---- PV: A = P (from per-wave LDS), B = V^T-frags (shared by groups) ----
    bf16x8 pa[2][2];
#pragma unroll
    for (int gq = 0; gq < 2; ++gq)
#pragma unroll
      for (int th = 0; th < 2; ++th)
        pa[gq][th] = *(const bf16x8*)(&P_lds[w][(gq * 16 + l15) * 72 + th * 32 + g * 8]);
#pragma unroll
    for (int dt = 0; dt < 4; ++dt) {
      const int vrow = dt * 16 + l15;
      const bf16x8 v0 = *(const bf16x8*)(&Vs[vrow * 64 + ((( 0 + g * 16) ^ sw) >> 1)]);
      const bf16x8 v1 = *(const bf16x8*)(&Vs[vrow * 64 + (((64 + g * 16) ^ sw) >> 1)]);
      o[0][dt] = __builtin_amdgcn_mfma_f32_16x16x32_bf16(pa[0][0], v0, o[0][dt], 0, 0, 0);
      o[0][dt] = __builtin_amdgcn_mfma_f32_16x16x32_bf16(pa[0][1], v1, o[0][dt], 0, 0, 0);
      o[1][dt] = __builtin_amdgcn_mfma_f32_16x16x32_bf16(pa[1][0], v0, o[1][dt], 0, 0, 0);
      o[1][dt] = __builtin_amdgcn_mfma_f32_16x16x32_bf16(pa[1][1], v1, o[1][dt], 0, 0, 0);
    }
    __syncthreads();  // all waves done reading Ks/Vs
    if (t16 < 15) {
      *(uint4*)(&Ks[tid * 16])     = rk0;
      *(uint4*)(&Ks[tid * 16 + 8]) = rk1;
      *(uint4*)(&Vs[tid * 16])     = rv0;
      *(uint4*)(&Vs[tid * 16 + 8]) = rv1;
      __syncthreads();  // staged tile visible
    }
  }

#pragma unroll
  for (int gq = 0; gq < 2; ++gq) {
    float sr[4];
#pragma unroll
    for (int r = 0; r < 4; ++r) sr[r] = 1.0f / __shfl(s_run[gq], g * 4 + r);
#pragma unroll
    for (int dt = 0; dt < 4; ++dt)
#pragma unroll
      for (int r = 0; r < 4; ++r)
        outp[(size_t)(nb * SEQ + q0 + gq * 16 + g * 4 + r) * HID + h * DHEAD + dt * 16 + l15] =
            f2bf(o[gq][dt][r] * sr[r]);
  }
}

extern "C" void kernel_launch(void* const* d_in, const int* in_sizes, int n_in,
                              void* d_out, int out_size, void* d_ws, size_t ws_size,
                              hipStream_t stream) {
  const float* x    = (const float*)d_in[0];
  const float* ln0g = (const float*)d_in[1];
  const float* ln0b = (const float*)d_in[2];
  const float* wq   = (const float*)d_in[3];
  const float* bq   = (const float*)d_in[4];
  const float* wk   = (const float*)d_in[5];
  const float* bk   = (const float*)d_in[6];
  const float* wv   = (const float*)d_in[7];
  const float* bv   = (const float*)d_in[8];
  const float* wo   = (const float*)d_in[9];
  const float* bo   = (const float*)d_in[10];
  const float* ln1g = (const float*)d_in[11];
  const float* ln1b = (const float*)d_in[12];
  const float* w1   = (const float*)d_in[13];
  const float* b1   = (const float*)d_in[14];
  const float* w2   = (const float*)d_in[15];
  const float* b2   = (const float*)d_in[16];
  float* out = (float*)d_out;

  char* ws = (char*)d_ws;
  // workspace layout (bytes)
  unsigned short* qkvT = (unsigned short*)(ws + 0);          // 3072x1024 bf16   (6 MB)
  unsigned short* woT  = (unsigned short*)(ws + 6291456);    // 1024x1024 bf16   (2 MB)
  unsigned short* w1T  = (unsigned short*)(ws + 8388608);    // 4096x1024 bf16   (8 MB)
  unsigned short* w2T  = (unsigned short*)(ws + 16777216);   // 1024x4096 bf16   (8 MB)
  float*          bqkv = (float*)(ws + 25165824);            // 3072 f32
  unsigned short* ybuf = (unsigned short*)(ws + 25178112);   // 8192x1024 bf16   (16 MB)
  unsigned short* qkv  = (unsigned short*)(ws + 41955328);   // 8192x3072 bf16   (48 MB)
  unsigned short* att  = (unsigned short*)(ws + 92286976);   // 8192x1024 bf16   (16 MB)
  unsigned short* hbuf = qkv;   // 8192x4096 bf16 (64 MB) overlays qkv+att (both dead)
  unsigned short* vT   = ybuf;  // 128x64x1024 bf16 (16 MB) overlays ybuf (dead between QKV-GEMM and LN1)

  const int M = NBATCH * SEQ;  // 8192

  // weight prep
  k_transpose<<<dim3(32, 32),  256, 0, stream>>>(wq, qkvT,                        HID,  HID);
  k_transpose<<<dim3(32, 32),  256, 0, stream>>>(wk, qkvT + (size_t)1024 * HID,   HID,  HID);
  k_transpose<<<dim3(32, 32),  256, 0, stream>>>(wv, qkvT + (size_t)2048 * HID,   HID,  HID);
  k_transpose<<<dim3(32, 32),  256, 0, stream>>>(wo, woT,                         HID,  HID);
  k_transpose<<<dim3(128, 32), 256, 0, stream>>>(w1, w1T,                         HID,  MLPD);
  k_transpose<<<dim3(32, 128), 256, 0, stream>>>(w2, w2T,                         MLPD, HID);
  k_pack_bias<<<dim3(12), 256, 0, stream>>>(bq, bk, bv, bqkv);

  // LN0 -> y
  k_ln<<<dim3(M), 256, 0, stream>>>(x, ln0g, ln0b, ybuf);
  // QKV: qkv = y @ [wq|wk|wv] + b   (M x 3072)
  k_gemm<0><<<dim3(24, 64), 256, 0, stream>>>(ybuf, qkvT, bqkv, nullptr, (void*)qkv, M, 3 * HID, HID);
  // V^T materialization (ybuf is dead now)
  k_vt<<<dim3(16, 128), 256, 0, stream>>>(qkv, vT);
  // attention
  k_attn<<<dim3(8, 128), 256, 0, stream>>>(qkv, vT, att);
  // x1 = x + att @ wo + bo  -> d_out (f32)
  k_gemm<2><<<dim3(8, 64), 256, 0, stream>>>(att, woT, bo, x, (void*)out, M, HID, HID);
  // LN1 -> y
  k_ln<<<dim3(M), 256, 0, stream>>>(out, ln1g, ln1b, ybuf);
  // h = gelu(y @ w1 + b1)  (M x 4096)
  k_gemm<1><<<dim3(32, 64), 256, 0, stream>>>(ybuf, w1T, b1, nullptr, (void*)hbuf, M, MLPD, HID);
  // out = d_out + h @ w2 + b2
  k_gemm<2><<<dim3(8, 64), 256, 0, stream>>>(hbuf, w2T, b2, out, (void*)out, M, HID, MLPD);
}

// Round 5
// 456.265 us; speedup vs baseline: 1.3682x; 1.0281x over previous
//
#include <hip/hip_runtime.h>
#include <math.h>

typedef __attribute__((ext_vector_type(8))) __bf16 bf16x8;
typedef __attribute__((ext_vector_type(4))) float f32x4;

#define NBATCH 8
#define SEQ    1024
#define NHEAD  16
#define DHEAD  64
#define HID    1024
#define MLPD   4096

static __device__ __forceinline__ unsigned short f2bf(float f) {
  unsigned int u = __float_as_uint(f);
  u += 0x7fffu + ((u >> 16) & 1u);
  return (unsigned short)(u >> 16);
}

// async global->LDS, 16B per lane; LDS dest is wave-uniform base + lane*16
static __device__ __forceinline__ void gload_lds16(const unsigned short* g,
                                                   unsigned short* l) {
  __builtin_amdgcn_global_load_lds(
      (const __attribute__((address_space(1))) unsigned int*)g,
      (__attribute__((address_space(3))) unsigned int*)l, 16, 0, 0);
}

// ---------- transpose: in f32 (R x C) -> out bf16 (C x R) ----------
__global__ __launch_bounds__(256) void k_transpose(const float* __restrict__ in,
                                                   unsigned short* __restrict__ out,
                                                   int R, int C) {
  __shared__ float t[32][33];
  const int tx = threadIdx.x & 31, ty = threadIdx.x >> 5;  // 32 x 8
  const int c0 = blockIdx.x * 32, r0 = blockIdx.y * 32;
#pragma unroll
  for (int j = 0; j < 4; ++j)
    t[ty + j * 8][tx] = in[(size_t)(r0 + ty + j * 8) * C + c0 + tx];
  __syncthreads();
#pragma unroll
  for (int j = 0; j < 4; ++j)
    out[(size_t)(c0 + ty + j * 8) * R + r0 + tx] = f2bf(t[tx][ty + j * 8]);
}

// ---------- pack q/k/v biases into one 3072 vector ----------
__global__ void k_pack_bias(const float* __restrict__ bq, const float* __restrict__ bk,
                            const float* __restrict__ bv, float* __restrict__ o) {
  int i = blockIdx.x * 256 + threadIdx.x;
  if (i < 3 * HID) {
    float v = (i < HID) ? bq[i] : (i < 2 * HID ? bk[i - HID] : bv[i - 2 * HID]);
    o[i] = v;
  }
}

// ---------- layernorm: f32 row (1024) -> bf16 row ----------
__global__ __launch_bounds__(256) void k_ln(const float* __restrict__ x,
                                            const float* __restrict__ gw,
                                            const float* __restrict__ bw,
                                            unsigned short* __restrict__ y) {
  __shared__ float red[2][4];
  const int row = blockIdx.x;
  const int tid = threadIdx.x;
  const float4 v = ((const float4*)(x + (size_t)row * HID))[tid];
  float sum = v.x + v.y + v.z + v.w;
  float sq  = v.x * v.x + v.y * v.y + v.z * v.z + v.w * v.w;
#pragma unroll
  for (int off = 32; off >= 1; off >>= 1) {
    sum += __shfl_xor(sum, off);
    sq  += __shfl_xor(sq, off);
  }
  if ((tid & 63) == 0) { red[0][tid >> 6] = sum; red[1][tid >> 6] = sq; }
  __syncthreads();
  sum = red[0][0] + red[0][1] + red[0][2] + red[0][3];
  sq  = red[1][0] + red[1][1] + red[1][2] + red[1][3];
  const float mu  = sum * (1.0f / HID);
  const float var = sq * (1.0f / HID) - mu * mu;
  const float rs  = rsqrtf(var + 1e-5f);
  const float4 g4 = ((const float4*)gw)[tid];
  const float4 b4 = ((const float4*)bw)[tid];
  ushort4 ov;
  ov.x = f2bf((v.x - mu) * rs * g4.x + b4.x);
  ov.y = f2bf((v.y - mu) * rs * g4.y + b4.y);
  ov.z = f2bf((v.z - mu) * rs * g4.z + b4.z);
  ov.w = f2bf((v.w - mu) * rs * g4.w + b4.w);
  ((ushort4*)(y + (size_t)row * HID))[tid] = ov;
}

// ---------- NT GEMM: C(MxN) = A(MxK) * BT(NxK)^T, bf16 in, f32 acc ----------
// Staging via global_load_lds width=16 into linear LDS [128][32] (m97 structure).
template <int EPI>
__global__ __launch_bounds__(256) void k_gemm(const unsigned short* __restrict__ A,
                                              const unsigned short* __restrict__ BT,
                                              const float* __restrict__ bias,
                                              const float* __restrict__ res,
                                              void* __restrict__ Cout,
                                              int M, int N, int K) {
  __shared__ unsigned short As[128 * 32];
  __shared__ unsigned short Bs[128 * 32];
  const int tid  = threadIdx.x;
  const int lane = tid & 63;
  const int w    = tid >> 6;
  const int wr   = w >> 1, wc = w & 1;
  const int l15  = lane & 15, g = lane >> 4;
  const int m0 = blockIdx.y * 128, n0 = blockIdx.x * 128;

  f32x4 acc[4][4] = {};

  // per-lane global source matching the HW LDS layout (base + lane*16B):
  // lane covers row = wave*32 + i*16 + (lane>>2), col elems (lane&3)*8..+7
  const int lrow = lane >> 2;
  const int lcol = (lane & 3) * 8;
  const unsigned short* Ag = A  + (size_t)(m0 + w * 32 + lrow) * K + lcol;
  const unsigned short* Bg = BT + (size_t)(n0 + w * 32 + lrow) * K + lcol;
  unsigned short* Al0 = &As[(w * 32) * 32];
  unsigned short* Al1 = &As[(w * 32 + 16) * 32];
  unsigned short* Bl0 = &Bs[(w * 32) * 32];
  unsigned short* Bl1 = &Bs[(w * 32 + 16) * 32];

  for (int k0 = 0; k0 < K; k0 += 32) {
    gload_lds16(Ag + k0,                     Al0);
    gload_lds16(Ag + (size_t)16 * K + k0,    Al1);
    gload_lds16(Bg + k0,                     Bl0);
    gload_lds16(Bg + (size_t)16 * K + k0,    Bl1);
    __syncthreads();  // vmcnt(0) drain + all waves' tiles visible
    bf16x8 af[4], bfr[4];
#pragma unroll
    for (int m = 0; m < 4; ++m)
      af[m] = *(const bf16x8*)(&As[(wr * 64 + m * 16 + l15) * 32 + g * 8]);
#pragma unroll
    for (int n = 0; n < 4; ++n)
      bfr[n] = *(const bf16x8*)(&Bs[(wc * 64 + n * 16 + l15) * 32 + g * 8]);
#pragma unroll
    for (int m = 0; m < 4; ++m)
#pragma unroll
      for (int n = 0; n < 4; ++n)
        acc[m][n] = __builtin_amdgcn_mfma_f32_16x16x32_bf16(af[m], bfr[n], acc[m][n], 0, 0, 0);
    __syncthreads();  // all reads done before next tile overwrites
  }

#pragma unroll
  for (int m = 0; m < 4; ++m) {
#pragma unroll
    for (int n = 0; n < 4; ++n) {
      const int col = n0 + wc * 64 + n * 16 + l15;
      const float bc = bias[col];
#pragma unroll
      for (int r = 0; r < 4; ++r) {
        const int row = m0 + wr * 64 + m * 16 + g * 4 + r;
        const size_t idx = (size_t)row * N + col;
        float v = acc[m][n][r] + bc;
        if constexpr (EPI == 0) {
          ((unsigned short*)Cout)[idx] = f2bf(v);
        } else if constexpr (EPI == 1) {
          float tv = tanhf(0.7978845608028654f * (v + 0.044715f * v * v * v));
          ((unsigned short*)Cout)[idx] = f2bf(0.5f * v * (1.0f + tv));
        } else {
          ((float*)Cout)[idx] = v + res[idx];
        }
      }
    }
  }
}

// ---------- V transpose: qkv (M x 3072) V-columns -> vT [nh][64][1024] bf16 ----------
__global__ __launch_bounds__(256) void k_vt(const unsigned short* __restrict__ qkv,
                                            unsigned short* __restrict__ vT) {
  __shared__ unsigned short t[64][72];
  const int nh = blockIdx.y;           // nb*16 + h
  const int nb = nh >> 4, h = nh & 15;
  const int l0 = blockIdx.x * 64;
  const int tx = threadIdx.x & 7;      // 8 chunks of 8 d-elems
  const int ty = threadIdx.x >> 3;     // 32 l-rows
  const unsigned short* src = qkv + (size_t)(nb * SEQ + l0) * 3072 + 2048 + h * DHEAD;
#pragma unroll
  for (int j = 0; j < 2; ++j)
    *(uint4*)(&t[ty + j * 32][tx * 8]) =
        *(const uint4*)(&src[(size_t)(ty + j * 32) * 3072 + tx * 8]);
  __syncthreads();
  unsigned short* dst = vT + (size_t)nh * DHEAD * SEQ + l0;
#pragma unroll
  for (int j = 0; j < 2; ++j) {
    const int d = ty + j * 32;
    ushort4 a, b;
    a.x = t[tx * 8 + 0][d]; a.y = t[tx * 8 + 1][d];
    a.z = t[tx * 8 + 2][d]; a.w = t[tx * 8 + 3][d];
    b.x = t[tx * 8 + 4][d]; b.y = t[tx * 8 + 5][d];
    b.z = t[tx * 8 + 6][d]; b.w = t[tx * 8 + 7][d];
    *(ushort4*)(&dst[(size_t)d * SEQ + tx * 8])     = a;
    *(ushort4*)(&dst[(size_t)d * SEQ + tx * 8 + 4]) = b;
  }
}

// ---------- flash attention, LDS-staged K/V, swapped QK^T ----------
#define SOFTMAX_GROUP(S, gq)                                                       \
  {                                                                                \
    float mx = -INFINITY;                                                          \
    _Pragma("unroll") for (int c = 0; c < 4; ++c)                                  \
      _Pragma("unroll") for (int r = 0; r < 4; ++r)                                \
        mx = fmaxf(mx, S[c][r]);                                                   \
    mx = fmaxf(mx, __shfl_xor(mx, 16));                                            \
    mx = fmaxf(mx, __shfl_xor(mx, 32));                                            \
    const float mnew = fmaxf(m_run[gq], mx);                                       \
    const float sc = __expf(0.125f * (m_run[gq] - mnew));                          \
    m_run[gq] = mnew;                                                              \
    float ts = 0.0f;                                                               \
    _Pragma("unroll") for (int c = 0; c < 4; ++c) {                                \
      const float p0 = __expf(0.125f * (S[c][0] - mnew));                          \
      const float p1 = __expf(0.125f * (S[c][1] - mnew));                          \
      const float p2 = __expf(0.125f * (S[c][2] - mnew));                          \
      const float p3 = __expf(0.125f * (S[c][3] - mnew));                          \
      ts += (p0 + p1) + (p2 + p3);                                                 \
      const unsigned int lo = (unsigned int)f2bf(p0) | ((unsigned int)f2bf(p1) << 16); \
      const unsigned int hi = (unsigned int)f2bf(p2) | ((unsigned int)f2bf(p3) << 16); \
      *(uint2*)(&P_lds[w][((gq) * 16 + l15) * 72 + c * 16 + g * 4]) = make_uint2(lo, hi); \
    }                                                                              \
    ts += __shfl_xor(ts, 16);                                                      \
    ts += __shfl_xor(ts, 32);                                                      \
    s_run[gq] = s_run[gq] * sc + ts;                                               \
    const float scr0 = __shfl(sc, g * 4 + 0), scr1 = __shfl(sc, g * 4 + 1);        \
    const float scr2 = __shfl(sc, g * 4 + 2), scr3 = __shfl(sc, g * 4 + 3);        \
    _Pragma("unroll") for (int dt = 0; dt < 4; ++dt) {                             \
      o[gq][dt][0] *= scr0; o[gq][dt][1] *= scr1;                                  \
      o[gq][dt][2] *= scr2; o[gq][dt][3] *= scr3;                                  \
    }                                                                              \
  }

__global__ __launch_bounds__(256, 4) void k_attn(const unsigned short* __restrict__ qkv,
                                                 const unsigned short* __restrict__ vT,
                                                 unsigned short* __restrict__ outp) {
  __shared__ unsigned short Ks[64 * 64];           // 8 KB, swizzled
  __shared__ unsigned short Vs[64 * 64];           // 8 KB, swizzled
  __shared__ unsigned short P_lds[4][32 * 72];     // 18 KB, per-wave P
  const int tid  = threadIdx.x;
  const int lane = tid & 63;
  const int w    = tid >> 6;
  const int l15  = lane & 15, g = lane >> 4;
  const int nh = blockIdx.y;
  const int nb = nh >> 4, h = nh & 15;
  const int q0 = blockIdx.x * 128 + w * 32;        // wave's 32 q-rows
  const size_t RS = 3 * HID;

  const unsigned short* Qp = qkv + (size_t)(nb * SEQ + q0) * RS + h * DHEAD;
  const unsigned short* Kg = qkv + (size_t)(nb * SEQ) * RS + HID + h * DHEAD;
  const unsigned short* Vg = vT + (size_t)nh * DHEAD * SEQ;

  const int L0 = tid * 32, L1 = L0 + 16;
  const int kr0 = L0 >> 7, kc0 = (L0 & 127) ^ ((kr0 & 7) << 4);
  const int kr1 = L1 >> 7, kc1 = (L1 & 127) ^ ((kr1 & 7) << 4);

  bf16x8 aq[2][2];
#pragma unroll
  for (int gq = 0; gq < 2; ++gq)
#pragma unroll
    for (int t = 0; t < 2; ++t)
      aq[gq][t] = *(const bf16x8*)(&Qp[(size_t)(gq * 16 + l15) * RS + t * 32 + g * 8]);

  f32x4 o[2][4] = {};
  float m_run[2] = {-INFINITY, -INFINITY};
  float s_run[2] = {0.0f, 0.0f};

  uint4 rk0, rk1, rv0, rv1;
  rk0 = *(const uint4*)(Kg + (size_t)kr0 * RS + (kc0 >> 1));
  rk1 = *(const uint4*)(Kg + (size_t)kr1 * RS + (kc1 >> 1));
  rv0 = *(const uint4*)(Vg + (size_t)kr0 * SEQ + (kc0 >> 1));
  rv1 = *(const uint4*)(Vg + (size_t)kr1 * SEQ + (kc1 >> 1));
  *(uint4*)(&Ks[tid * 16])     = rk0;
  *(uint4*)(&Ks[tid * 16 + 8]) = rk1;
  *(uint4*)(&Vs[tid * 16])     = rv0;
  *(uint4*)(&Vs[tid * 16 + 8]) = rv1;
  __syncthreads();

  const int sw = (l15 & 7) << 4;  // byte-swizzle for fragment reads

  for (int t16 = 0; t16 < 16; ++t16) {
    if (t16 < 15) {
      const int kb = (t16 + 1) * 64;
      rk0 = *(const uint4*)(Kg + (size_t)(kb + kr0) * RS + (kc0 >> 1));
      rk1 = *(const uint4*)(Kg + (size_t)(kb + kr1) * RS + (kc1 >> 1));
      rv0 = *(const uint4*)(Vg + (size_t)kr0 * SEQ + kb + (kc0 >> 1));
      rv1 = *(const uint4*)(Vg + (size_t)kr1 * SEQ + kb + (kc1 >> 1));
    }

    f32x4 S0[4], S1[4];
#pragma unroll
    for (int c = 0; c < 4; ++c) {
      const int krow = c * 16 + l15;
      const bf16x8 k0 = *(const bf16x8*)(&Ks[krow * 64 + ((( 0 + g * 16) ^ sw) >> 1)]);
      const bf16x8 k1 = *(const bf16x8*)(&Ks[krow * 64 + (((64 + g * 16) ^ sw) >> 1)]);
      f32x4 a = {};
      a = __builtin_amdgcn_mfma_f32_16x16x32_bf16(k0, aq[0][0], a, 0, 0, 0);
      a = __builtin_amdgcn_mfma_f32_16x16x32_bf16(k1, aq[0][1], a, 0, 0, 0);
      S0[c] = a;
      f32x4 b = {};
      b = __builtin_amdgcn_mfma_f32_16x16x32_bf16(k0, aq[1][0], b, 0, 0, 0);
      b = __builtin_amdgcn_mfma_f32_16x16x32_bf16(k1, aq[1][1], b, 0, 0, 0);
      S1[c] = b;
    }

    SOFTMAX_GROUP(S0, 0)
    SOFTMAX_GROUP(S1, 1)

    bf16x8 pa[2][2];
#pragma unroll
    for (int gq = 0; gq < 2; ++gq)
#pragma unroll
      for (int th = 0; th < 2; ++th)
        pa[gq][th] = *(const bf16x8*)(&P_lds[w][(gq * 16 + l15) * 72 + th * 32 + g * 8]);
#pragma unroll
    for (int dt = 0; dt < 4; ++dt) {
      const int vrow = dt * 16 + l15;
      const bf16x8 v0 = *(const bf16x8*)(&Vs[vrow * 64 + ((( 0 + g * 16) ^ sw) >> 1)]);
      const bf16x8 v1 = *(const bf16x8*)(&Vs[vrow * 64 + (((64 + g * 16) ^ sw) >> 1)]);
      o[0][dt] = __builtin_amdgcn_mfma_f32_16x16x32_bf16(pa[0][0], v0, o[0][dt], 0, 0, 0);
      o[0][dt] = __builtin_amdgcn_mfma_f32_16x16x32_bf16(pa[0][1], v1, o[0][dt], 0, 0, 0);
      o[1][dt] = __builtin_amdgcn_mfma_f32_16x16x32_bf16(pa[1][0], v0, o[1][dt], 0, 0, 0);
      o[1][dt] = __builtin_amdgcn_mfma_f32_16x16x32_bf16(pa[1][1], v1, o[1][dt], 0, 0, 0);
    }
    __syncthreads();
    if (t16 < 15) {
      *(uint4*)(&Ks[tid * 16])     = rk0;
      *(uint4*)(&Ks[tid * 16 + 8]) = rk1;
      *(uint4*)(&Vs[tid * 16])     = rv0;
      *(uint4*)(&Vs[tid * 16 + 8]) = rv1;
      __syncthreads();
    }
  }

#pragma unroll
  for (int gq = 0; gq < 2; ++gq) {
    float sr[4];
#pragma unroll
    for (int r = 0; r < 4; ++r) sr[r] = 1.0f / __shfl(s_run[gq], g * 4 + r);
#pragma unroll
    for (int dt = 0; dt < 4; ++dt)
#pragma unroll
      for (int r = 0; r < 4; ++r)
        outp[(size_t)(nb * SEQ + q0 + gq * 16 + g * 4 + r) * HID + h * DHEAD + dt * 16 + l15] =
            f2bf(o[gq][dt][r] * sr[r]);
  }
}

extern "C" void kernel_launch(void* const* d_in, const int* in_sizes, int n_in,
                              void* d_out, int out_size, void* d_ws, size_t ws_size,
                              hipStream_t stream) {
  const float* x    = (const float*)d_in[0];
  const float* ln0g = (const float*)d_in[1];
  const float* ln0b = (const float*)d_in[2];
  const float* wq   = (const float*)d_in[3];
  const float* bq   = (const float*)d_in[4];
  const float* wk   = (const float*)d_in[5];
  const float* bk   = (const float*)d_in[6];
  const float* wv   = (const float*)d_in[7];
  const float* bv   = (const float*)d_in[8];
  const float* wo   = (const float*)d_in[9];
  const float* bo   = (const float*)d_in[10];
  const float* ln1g = (const float*)d_in[11];
  const float* ln1b = (const float*)d_in[12];
  const float* w1   = (const float*)d_in[13];
  const float* b1   = (const float*)d_in[14];
  const float* w2   = (const float*)d_in[15];
  const float* b2   = (const float*)d_in[16];
  float* out = (float*)d_out;

  char* ws = (char*)d_ws;
  unsigned short* qkvT = (unsigned short*)(ws + 0);          // 3072x1024 bf16   (6 MB)
  unsigned short* woT  = (unsigned short*)(ws + 6291456);    // 1024x1024 bf16   (2 MB)
  unsigned short* w1T  = (unsigned short*)(ws + 8388608);    // 4096x1024 bf16   (8 MB)
  unsigned short* w2T  = (unsigned short*)(ws + 16777216);   // 1024x4096 bf16   (8 MB)
  float*          bqkv = (float*)(ws + 25165824);            // 3072 f32
  unsigned short* ybuf = (unsigned short*)(ws + 25178112);   // 8192x1024 bf16   (16 MB)
  unsigned short* qkv  = (unsigned short*)(ws + 41955328);   // 8192x3072 bf16   (48 MB)
  unsigned short* att  = (unsigned short*)(ws + 92286976);   // 8192x1024 bf16   (16 MB)
  unsigned short* hbuf = qkv;   // 8192x4096 bf16 (64 MB) overlays qkv+att (both dead)
  unsigned short* vT   = ybuf;  // 128x64x1024 bf16 (16 MB) overlays ybuf (dead between QKV-GEMM and LN1)

  const int M = NBATCH * SEQ;  // 8192

  // weight prep
  k_transpose<<<dim3(32, 32),  256, 0, stream>>>(wq, qkvT,                        HID,  HID);
  k_transpose<<<dim3(32, 32),  256, 0, stream>>>(wk, qkvT + (size_t)1024 * HID,   HID,  HID);
  k_transpose<<<dim3(32, 32),  256, 0, stream>>>(wv, qkvT + (size_t)2048 * HID,   HID,  HID);
  k_transpose<<<dim3(32, 32),  256, 0, stream>>>(wo, woT,                         HID,  HID);
  k_transpose<<<dim3(128, 32), 256, 0, stream>>>(w1, w1T,                         HID,  MLPD);
  k_transpose<<<dim3(32, 128), 256, 0, stream>>>(w2, w2T,                         MLPD, HID);
  k_pack_bias<<<dim3(12), 256, 0, stream>>>(bq, bk, bv, bqkv);

  // LN0 -> y
  k_ln<<<dim3(M), 256, 0, stream>>>(x, ln0g, ln0b, ybuf);
  // QKV: qkv = y @ [wq|wk|wv] + b   (M x 3072)
  k_gemm<0><<<dim3(24, 64), 256, 0, stream>>>(ybuf, qkvT, bqkv, nullptr, (void*)qkv, M, 3 * HID, HID);
  // V^T materialization (ybuf is dead now)
  k_vt<<<dim3(16, 128), 256, 0, stream>>>(qkv, vT);
  // attention
  k_attn<<<dim3(8, 128), 256, 0, stream>>>(qkv, vT, att);
  // x1 = x + att @ wo + bo  -> d_out (f32)
  k_gemm<2><<<dim3(8, 64), 256, 0, stream>>>(att, woT, bo, x, (void*)out, M, HID, HID);
  // LN1 -> y
  k_ln<<<dim3(M), 256, 0, stream>>>(out, ln1g, ln1b, ybuf);
  // h = gelu(y @ w1 + b1)  (M x 4096)
  k_gemm<1><<<dim3(32, 64), 256, 0, stream>>>(ybuf, w1T, b1, nullptr, (void*)hbuf, M, MLPD, HID);
  // out = d_out + h @ w2 + b2
  k_gemm<2><<<dim3(8, 64), 256, 0, stream>>>(hbuf, w2T, b2, out, (void*)out, M, HID, MLPD);
}

// Round 7
// 441.469 us; speedup vs baseline: 1.4141x; 1.0335x over previous
//
#include <hip/hip_runtime.h>
#include <math.h>

typedef __attribute__((ext_vector_type(8))) __bf16 bf16x8;
typedef __attribute__((ext_vector_type(4))) float f32x4;

#define NBATCH 8
#define SEQ    1024
#define NHEAD  16
#define DHEAD  64
#define HID    1024
#define MLPD   4096

static __device__ __forceinline__ unsigned short f2bf(float f) {
  unsigned int u = __float_as_uint(f);
  u += 0x7fffu + ((u >> 16) & 1u);
  return (unsigned short)(u >> 16);
}

// async global->LDS, 16B per lane; LDS dest is wave-uniform base + lane*16
static __device__ __forceinline__ void gload_lds16(const unsigned short* g,
                                                   unsigned short* l) {
  __builtin_amdgcn_global_load_lds(
      (const __attribute__((address_space(1))) unsigned int*)g,
      (__attribute__((address_space(3))) unsigned int*)l, 16, 0, 0);
}

// exact tanh-gelu via __expf (cheap): tanh(z) = sign(z)*(1-e^{-2|z|})/(1+e^{-2|z|})
static __device__ __forceinline__ float gelu_fast(float v) {
  const float z = 0.7978845608028654f * (v + 0.044715f * v * v * v);
  const float e = __expf(-2.0f * fabsf(z));
  float th = (1.0f - e) / (1.0f + e);
  th = copysignf(th, z);
  return 0.5f * v * (1.0f + th);
}

// ---------- transpose: in f32 (R x C) -> out bf16 (C x R) ----------
__global__ __launch_bounds__(256) void k_transpose(const float* __restrict__ in,
                                                   unsigned short* __restrict__ out,
                                                   int R, int C) {
  __shared__ float t[32][33];
  const int tx = threadIdx.x & 31, ty = threadIdx.x >> 5;  // 32 x 8
  const int c0 = blockIdx.x * 32, r0 = blockIdx.y * 32;
#pragma unroll
  for (int j = 0; j < 4; ++j)
    t[ty + j * 8][tx] = in[(size_t)(r0 + ty + j * 8) * C + c0 + tx];
  __syncthreads();
#pragma unroll
  for (int j = 0; j < 4; ++j)
    out[(size_t)(c0 + ty + j * 8) * R + r0 + tx] = f2bf(t[tx][ty + j * 8]);
}

// ---------- pack q/k/v biases into one 3072 vector ----------
__global__ void k_pack_bias(const float* __restrict__ bq, const float* __restrict__ bk,
                            const float* __restrict__ bv, float* __restrict__ o) {
  int i = blockIdx.x * 256 + threadIdx.x;
  if (i < 3 * HID) {
    float v = (i < HID) ? bq[i] : (i < 2 * HID ? bk[i - HID] : bv[i - 2 * HID]);
    o[i] = v;
  }
}

// ---------- layernorm: f32 row (1024) -> bf16 row ----------
__global__ __launch_bounds__(256) void k_ln(const float* __restrict__ x,
                                            const float* __restrict__ gw,
                                            const float* __restrict__ bw,
                                            unsigned short* __restrict__ y) {
  __shared__ float red[2][4];
  const int row = blockIdx.x;
  const int tid = threadIdx.x;
  const float4 v = ((const float4*)(x + (size_t)row * HID))[tid];
  float sum = v.x + v.y + v.z + v.w;
  float sq  = v.x * v.x + v.y * v.y + v.z * v.z + v.w * v.w;
#pragma unroll
  for (int off = 32; off >= 1; off >>= 1) {
    sum += __shfl_xor(sum, off);
    sq  += __shfl_xor(sq, off);
  }
  if ((tid & 63) == 0) { red[0][tid >> 6] = sum; red[1][tid >> 6] = sq; }
  __syncthreads();
  sum = red[0][0] + red[0][1] + red[0][2] + red[0][3];
  sq  = red[1][0] + red[1][1] + red[1][2] + red[1][3];
  const float mu  = sum * (1.0f / HID);
  const float var = sq * (1.0f / HID) - mu * mu;
  const float rs  = rsqrtf(var + 1e-5f);
  const float4 g4 = ((const float4*)gw)[tid];
  const float4 b4 = ((const float4*)bw)[tid];
  ushort4 ov;
  ov.x = f2bf((v.x - mu) * rs * g4.x + b4.x);
  ov.y = f2bf((v.y - mu) * rs * g4.y + b4.y);
  ov.z = f2bf((v.z - mu) * rs * g4.z + b4.z);
  ov.w = f2bf((v.w - mu) * rs * g4.w + b4.w);
  ((ushort4*)(y + (size_t)row * HID))[tid] = ov;
}

// ---------- NT GEMM: C(MxN) = A(MxK) * BT(NxK)^T, bf16 in, f32 acc ----------
// Double-buffered LDS via global_load_lds (stage t+1 before compute t; single
// __syncthreads per K-step whose vmcnt-drain is hidden under the MFMAs).
// EPI 0/1: LDS-staged wide epilogue -> full-line 128B coalesced bf16 stores.
template <int EPI>
__global__ __launch_bounds__(256) void k_gemm(const unsigned short* __restrict__ A,
                                              const unsigned short* __restrict__ BT,
                                              const float* __restrict__ bias,
                                              const float* __restrict__ res,
                                              void* __restrict__ Cout,
                                              int M, int N, int K) {
  __shared__ unsigned short As[2][128 * 32];
  __shared__ unsigned short Bs[2][128 * 32];
  const int tid  = threadIdx.x;
  const int lane = tid & 63;
  const int w    = tid >> 6;
  const int wr   = w >> 1, wc = w & 1;
  const int l15  = lane & 15, g = lane >> 4;

  // XCD-aware bijective block swizzle (grid size divisible by 8 for all calls)
  const int gx = gridDim.x;
  const int nwg = gx * gridDim.y;
  int lid = blockIdx.y * gx + blockIdx.x;
  lid = (lid & 7) * (nwg >> 3) + (lid >> 3);
  const int m0 = (lid / gx) * 128, n0 = (lid % gx) * 128;

  f32x4 acc[4][4] = {};

  // staging: lane covers row = w*32 + {0,16} + (lane>>2), cols (lane&3)*8..+7
  const int lrow = lane >> 2;
  const int lcol = (lane & 3) * 8;
  const unsigned short* Ag = A  + (size_t)(m0 + w * 32 + lrow) * K + lcol;
  const unsigned short* Bg = BT + (size_t)(n0 + w * 32 + lrow) * K + lcol;
  const int dst0 = (w * 32) * 32;
  const int dst1 = (w * 32 + 16) * 32;

#define STAGE_G(buf, kk)                                        \
  do {                                                          \
    gload_lds16(Ag + (kk),                 &As[buf][dst0]);     \
    gload_lds16(Ag + (size_t)16 * K + (kk), &As[buf][dst1]);    \
    gload_lds16(Bg + (kk),                 &Bs[buf][dst0]);     \
    gload_lds16(Bg + (size_t)16 * K + (kk), &Bs[buf][dst1]);    \
  } while (0)

  STAGE_G(0, 0);
  __syncthreads();
  int cur = 0;
  for (int k0 = 0; k0 < K; k0 += 32) {
    if (k0 + 32 < K) STAGE_G(cur ^ 1, k0 + 32);  // issue early, lands by barrier
    bf16x8 af[4], bfr[4];
#pragma unroll
    for (int m = 0; m < 4; ++m)
      af[m] = *(const bf16x8*)(&As[cur][(wr * 64 + m * 16 + l15) * 32 + g * 8]);
#pragma unroll
    for (int n = 0; n < 4; ++n)
      bfr[n] = *(const bf16x8*)(&Bs[cur][(wc * 64 + n * 16 + l15) * 32 + g * 8]);
#pragma unroll
    for (int m = 0; m < 4; ++m)
#pragma unroll
      for (int n = 0; n < 4; ++n)
        acc[m][n] = __builtin_amdgcn_mfma_f32_16x16x32_bf16(af[m], bfr[n], acc[m][n], 0, 0, 0);
    __syncthreads();  // drains staged loads (hidden under MFMAs) + read fence
    cur ^= 1;
  }
#undef STAGE_G

  if constexpr (EPI == 2) {
    // f32 out + residual: 16-lane x 4B = full 64B lines already
#pragma unroll
    for (int m = 0; m < 4; ++m) {
#pragma unroll
      for (int n = 0; n < 4; ++n) {
        const int col = n0 + wc * 64 + n * 16 + l15;
        const float bc = bias[col];
#pragma unroll
        for (int r = 0; r < 4; ++r) {
          const int row = m0 + wr * 64 + m * 16 + g * 4 + r;
          const size_t idx = (size_t)row * N + col;
          ((float*)Cout)[idx] = acc[m][n][r] + bc + res[idx];
        }
      }
    }
  } else {
    // bf16 out: route through per-wave 64x64 LDS tile -> 128B coalesced stores
    unsigned short* ep = (w < 2) ? &As[w][0] : &Bs[w - 2][0];
#pragma unroll
    for (int m = 0; m < 4; ++m) {
#pragma unroll
      for (int n = 0; n < 4; ++n) {
        const float bc = bias[n0 + wc * 64 + n * 16 + l15];
#pragma unroll
        for (int r = 0; r < 4; ++r) {
          float v = acc[m][n][r] + bc;
          if constexpr (EPI == 1) v = gelu_fast(v);
          ep[(m * 16 + g * 4 + r) * 64 + n * 16 + l15] = f2bf(v);
        }
      }
    }
    // 64x64 bf16 tile = 512 uint4; 64 lanes x 8 = 512 (j<8, NOT j<4!)
#pragma unroll
    for (int j = 0; j < 8; ++j) {
      const int t = lane + j * 64;         // uint4 index 0..511
      const int row = t >> 3, colb = (t & 7) * 8;
      const uint4 vv = *(const uint4*)(ep + row * 64 + colb);
      unsigned short* outp = (unsigned short*)Cout +
          (size_t)(m0 + wr * 64 + row) * N + n0 + wc * 64 + colb;
      *(uint4*)outp = vv;
    }
  }
}

// ---------- V transpose: qkv (M x 3072) V-columns -> vT [nh][64][1024] bf16 ----------
__global__ __launch_bounds__(256) void k_vt(const unsigned short* __restrict__ qkv,
                                            unsigned short* __restrict__ vT) {
  __shared__ unsigned short t[64][72];
  const int nh = blockIdx.y;           // nb*16 + h
  const int nb = nh >> 4, h = nh & 15;
  const int l0 = blockIdx.x * 64;
  const int tx = threadIdx.x & 7;      // 8 chunks of 8 d-elems
  const int ty = threadIdx.x >> 3;     // 32 l-rows
  const unsigned short* src = qkv + (size_t)(nb * SEQ + l0) * 3072 + 2048 + h * DHEAD;
#pragma unroll
  for (int j = 0; j < 2; ++j)
    *(uint4*)(&t[ty + j * 32][tx * 8]) =
        *(const uint4*)(&src[(size_t)(ty + j * 32) * 3072 + tx * 8]);
  __syncthreads();
  unsigned short* dst = vT + (size_t)nh * DHEAD * SEQ + l0;
#pragma unroll
  for (int j = 0; j < 2; ++j) {
    const int d = ty + j * 32;
    ushort4 a, b;
    a.x = t[tx * 8 + 0][d]; a.y = t[tx * 8 + 1][d];
    a.z = t[tx * 8 + 2][d]; a.w = t[tx * 8 + 3][d];
    b.x = t[tx * 8 + 4][d]; b.y = t[tx * 8 + 5][d];
    b.z = t[tx * 8 + 6][d]; b.w = t[tx * 8 + 7][d];
    *(ushort4*)(&dst[(size_t)d * SEQ + tx * 8])     = a;
    *(ushort4*)(&dst[(size_t)d * SEQ + tx * 8 + 4]) = b;
  }
}

// ---------- flash attention, LDS-staged K/V, swapped QK^T ----------
#define SOFTMAX_GROUP(S, gq)                                                       \
  {                                                                                \
    float mx = -INFINITY;                                                          \
    _Pragma("unroll") for (int c = 0; c < 4; ++c)                                  \
      _Pragma("unroll") for (int r = 0; r < 4; ++r)                                \
        mx = fmaxf(mx, S[c][r]);                                                   \
    mx = fmaxf(mx, __shfl_xor(mx, 16));                                            \
    mx = fmaxf(mx, __shfl_xor(mx, 32));                                            \
    const float mnew = fmaxf(m_run[gq], mx);                                       \
    const float sc = __expf(0.125f * (m_run[gq] - mnew));                          \
    m_run[gq] = mnew;                                                              \
    float ts = 0.0f;                                                               \
    _Pragma("unroll") for (int c = 0; c < 4; ++c) {                                \
      const float p0 = __expf(0.125f * (S[c][0] - mnew));                          \
      const float p1 = __expf(0.125f * (S[c][1] - mnew));                          \
      const float p2 = __expf(0.125f * (S[c][2] - mnew));                          \
      const float p3 = __expf(0.125f * (S[c][3] - mnew));                          \
      ts += (p0 + p1) + (p2 + p3);                                                 \
      const unsigned int lo = (unsigned int)f2bf(p0) | ((unsigned int)f2bf(p1) << 16); \
      const unsigned int hi = (unsigned int)f2bf(p2) | ((unsigned int)f2bf(p3) << 16); \
      *(uint2*)(&P_lds[w][((gq) * 16 + l15) * 72 + c * 16 + g * 4]) = make_uint2(lo, hi); \
    }                                                                              \
    ts += __shfl_xor(ts, 16);                                                      \
    ts += __shfl_xor(ts, 32);                                                      \
    s_run[gq] = s_run[gq] * sc + ts;                                               \
    const float scr0 = __shfl(sc, g * 4 + 0), scr1 = __shfl(sc, g * 4 + 1);        \
    const float scr2 = __shfl(sc, g * 4 + 2), scr3 = __shfl(sc, g * 4 + 3);        \
    _Pragma("unroll") for (int dt = 0; dt < 4; ++dt) {                             \
      o[gq][dt][0] *= scr0; o[gq][dt][1] *= scr1;                                  \
      o[gq][dt][2] *= scr2; o[gq][dt][3] *= scr3;                                  \
    }                                                                              \
  }

__global__ __launch_bounds__(256, 4) void k_attn(const unsigned short* __restrict__ qkv,
                                                 const unsigned short* __restrict__ vT,
                                                 unsigned short* __restrict__ outp) {
  __shared__ unsigned short Ks[64 * 64];           // 8 KB, swizzled
  __shared__ unsigned short Vs[64 * 64];           // 8 KB, swizzled
  __shared__ unsigned short P_lds[4][32 * 72];     // 18 KB, per-wave P
  const int tid  = threadIdx.x;
  const int lane = tid & 63;
  const int w    = tid >> 6;
  const int l15  = lane & 15, g = lane >> 4;
  const int nh = blockIdx.y;
  const int nb = nh >> 4, h = nh & 15;
  const int q0 = blockIdx.x * 128 + w * 32;        // wave's 32 q-rows
  const size_t RS = 3 * HID;

  const unsigned short* Qp = qkv + (size_t)(nb * SEQ + q0) * RS + h * DHEAD;
  const unsigned short* Kg = qkv + (size_t)(nb * SEQ) * RS + HID + h * DHEAD;
  const unsigned short* Vg = vT + (size_t)nh * DHEAD * SEQ;

  const int L0 = tid * 32, L1 = L0 + 16;
  const int kr0 = L0 >> 7, kc0 = (L0 & 127) ^ ((kr0 & 7) << 4);
  const int kr1 = L1 >> 7, kc1 = (L1 & 127) ^ ((kr1 & 7) << 4);

  bf16x8 aq[2][2];
#pragma unroll
  for (int gq = 0; gq < 2; ++gq)
#pragma unroll
    for (int t = 0; t < 2; ++t)
      aq[gq][t] = *(const bf16x8*)(&Qp[(size_t)(gq * 16 + l15) * RS + t * 32 + g * 8]);

  f32x4 o[2][4] = {};
  float m_run[2] = {-INFINITY, -INFINITY};
  float s_run[2] = {0.0f, 0.0f};

  uint4 rk0, rk1, rv0, rv1;
  rk0 = *(const uint4*)(Kg + (size_t)kr0 * RS + (kc0 >> 1));
  rk1 = *(const uint4*)(Kg + (size_t)kr1 * RS + (kc1 >> 1));
  rv0 = *(const uint4*)(Vg + (size_t)kr0 * SEQ + (kc0 >> 1));
  rv1 = *(const uint4*)(Vg + (size_t)kr1 * SEQ + (kc1 >> 1));
  *(uint4*)(&Ks[tid * 16])     = rk0;
  *(uint4*)(&Ks[tid * 16 + 8]) = rk1;
  *(uint4*)(&Vs[tid * 16])     = rv0;
  *(uint4*)(&Vs[tid * 16 + 8]) = rv1;
  __syncthreads();

  const int sw = (l15 & 7) << 4;  // byte-swizzle for fragment reads

  for (int t16 = 0; t16 < 16; ++t16) {
    if (t16 < 15) {
      const int kb = (t16 + 1) * 64;
      rk0 = *(const uint4*)(Kg + (size_t)(kb + kr0) * RS + (kc0 >> 1));
      rk1 = *(const uint4*)(Kg + (size_t)(kb + kr1) * RS + (kc1 >> 1));
      rv0 = *(const uint4*)(Vg + (size_t)kr0 * SEQ + kb + (kc0 >> 1));
      rv1 = *(const uint4*)(Vg + (size_t)kr1 * SEQ + kb + (kc1 >> 1));
    }

    f32x4 S0[4], S1[4];
#pragma unroll
    for (int c = 0; c < 4; ++c) {
      const int krow = c * 16 + l15;
      const bf16x8 k0 = *(const bf16x8*)(&Ks[krow * 64 + ((( 0 + g * 16) ^ sw) >> 1)]);
      const bf16x8 k1 = *(const bf16x8*)(&Ks[krow * 64 + (((64 + g * 16) ^ sw) >> 1)]);
      f32x4 a = {};
      a = __builtin_amdgcn_mfma_f32_16x16x32_bf16(k0, aq[0][0], a, 0, 0, 0);
      a = __builtin_amdgcn_mfma_f32_16x16x32_bf16(k1, aq[0][1], a, 0, 0, 0);
      S0[c] = a;
      f32x4 b = {};
      b = __builtin_amdgcn_mfma_f32_16x16x32_bf16(k0, aq[1][0], b, 0, 0, 0);
      b = __builtin_amdgcn_mfma_f32_16x16x32_bf16(k1, aq[1][1], b, 0, 0, 0);
      S1[c] = b;
    }

    SOFTMAX_GROUP(S0, 0)
    SOFTMAX_GROUP(S1, 1)

    bf16x8 pa[2][2];
#pragma unroll
    for (int gq = 0; gq < 2; ++gq)
#pragma unroll
      for (int th = 0; th < 2; ++th)
        pa[gq][th] = *(const bf16x8*)(&P_lds[w][(gq * 16 + l15) * 72 + th * 32 + g * 8]);
#pragma unroll
    for (int dt = 0; dt < 4; ++dt) {
      const int vrow = dt * 16 + l15;
      const bf16x8 v0 = *(const bf16x8*)(&Vs[vrow * 64 + ((( 0 + g * 16) ^ sw) >> 1)]);
      const bf16x8 v1 = *(const bf16x8*)(&Vs[vrow * 64 + (((64 + g * 16) ^ sw) >> 1)]);
      o[0][dt] = __builtin_amdgcn_mfma_f32_16x16x32_bf16(pa[0][0], v0, o[0][dt], 0, 0, 0);
      o[0][dt] = __builtin_amdgcn_mfma_f32_16x16x32_bf16(pa[0][1], v1, o[0][dt], 0, 0, 0);
      o[1][dt] = __builtin_amdgcn_mfma_f32_16x16x32_bf16(pa[1][0], v0, o[1][dt], 0, 0, 0);
      o[1][dt] = __builtin_amdgcn_mfma_f32_16x16x32_bf16(pa[1][1], v1, o[1][dt], 0, 0, 0);
    }
    __syncthreads();
    if (t16 < 15) {
      *(uint4*)(&Ks[tid * 16])     = rk0;
      *(uint4*)(&Ks[tid * 16 + 8]) = rk1;
      *(uint4*)(&Vs[tid * 16])     = rv0;
      *(uint4*)(&Vs[tid * 16 + 8]) = rv1;
      __syncthreads();
    }
  }

#pragma unroll
  for (int gq = 0; gq < 2; ++gq) {
    float sr[4];
#pragma unroll
    for (int r = 0; r < 4; ++r) sr[r] = 1.0f / __shfl(s_run[gq], g * 4 + r);
#pragma unroll
    for (int dt = 0; dt < 4; ++dt)
#pragma unroll
      for (int r = 0; r < 4; ++r)
        outp[(size_t)(nb * SEQ + q0 + gq * 16 + g * 4 + r) * HID + h * DHEAD + dt * 16 + l15] =
            f2bf(o[gq][dt][r] * sr[r]);
  }
}

extern "C" void kernel_launch(void* const* d_in, const int* in_sizes, int n_in,
                              void* d_out, int out_size, void* d_ws, size_t ws_size,
                              hipStream_t stream) {
  const float* x    = (const float*)d_in[0];
  const float* ln0g = (const float*)d_in[1];
  const float* ln0b = (const float*)d_in[2];
  const float* wq   = (const float*)d_in[3];
  const float* bq   = (const float*)d_in[4];
  const float* wk   = (const float*)d_in[5];
  const float* bk   = (const float*)d_in[6];
  const float* wv   = (const float*)d_in[7];
  const float* bv   = (const float*)d_in[8];
  const float* wo   = (const float*)d_in[9];
  const float* bo   = (const float*)d_in[10];
  const float* ln1g = (const float*)d_in[11];
  const float* ln1b = (const float*)d_in[12];
  const float* w1   = (const float*)d_in[13];
  const float* b1   = (const float*)d_in[14];
  const float* w2   = (const float*)d_in[15];
  const float* b2   = (const float*)d_in[16];
  float* out = (float*)d_out;

  char* ws = (char*)d_ws;
  unsigned short* qkvT = (unsigned short*)(ws + 0);          // 3072x1024 bf16   (6 MB)
  unsigned short* woT  = (unsigned short*)(ws + 6291456);    // 1024x1024 bf16   (2 MB)
  unsigned short* w1T  = (unsigned short*)(ws + 8388608);    // 4096x1024 bf16   (8 MB)
  unsigned short* w2T  = (unsigned short*)(ws + 16777216);   // 1024x4096 bf16   (8 MB)
  float*          bqkv = (float*)(ws + 25165824);            // 3072 f32
  unsigned short* ybuf = (unsigned short*)(ws + 25178112);   // 8192x1024 bf16   (16 MB)
  unsigned short* qkv  = (unsigned short*)(ws + 41955328);   // 8192x3072 bf16   (48 MB)
  unsigned short* att  = (unsigned short*)(ws + 92286976);   // 8192x1024 bf16   (16 MB)
  unsigned short* hbuf = qkv;   // 8192x4096 bf16 (64 MB) overlays qkv+att (both dead)
  unsigned short* vT   = ybuf;  // 128x64x1024 bf16 (16 MB) overlays ybuf (dead between QKV-GEMM and LN1)

  const int M = NBATCH * SEQ;  // 8192

  // weight prep
  k_transpose<<<dim3(32, 32),  256, 0, stream>>>(wq, qkvT,                        HID,  HID);
  k_transpose<<<dim3(32, 32),  256, 0, stream>>>(wk, qkvT + (size_t)1024 * HID,   HID,  HID);
  k_transpose<<<dim3(32, 32),  256, 0, stream>>>(wv, qkvT + (size_t)2048 * HID,   HID,  HID);
  k_transpose<<<dim3(32, 32),  256, 0, stream>>>(wo, woT,                         HID,  HID);
  k_transpose<<<dim3(128, 32), 256, 0, stream>>>(w1, w1T,                         HID,  MLPD);
  k_transpose<<<dim3(32, 128), 256, 0, stream>>>(w2, w2T,                         MLPD, HID);
  k_pack_bias<<<dim3(12), 256, 0, stream>>>(bq, bk, bv, bqkv);

  // LN0 -> y
  k_ln<<<dim3(M), 256, 0, stream>>>(x, ln0g, ln0b, ybuf);
  // QKV: qkv = y @ [wq|wk|wv] + b   (M x 3072)
  k_gemm<0><<<dim3(24, 64), 256, 0, stream>>>(ybuf, qkvT, bqkv, nullptr, (void*)qkv, M, 3 * HID, HID);
  // V^T materialization (ybuf is dead now)
  k_vt<<<dim3(16, 128), 256, 0, stream>>>(qkv, vT);
  // attention
  k_attn<<<dim3(8, 128), 256, 0, stream>>>(qkv, vT, att);
  // x1 = x + att @ wo + bo  -> d_out (f32)
  k_gemm<2><<<dim3(8, 64), 256, 0, stream>>>(att, woT, bo, x, (void*)out, M, HID, HID);
  // LN1 -> y
  k_ln<<<dim3(M), 256, 0, stream>>>(out, ln1g, ln1b, ybuf);
  // h = gelu(y @ w1 + b1)  (M x 4096)
  k_gemm<1><<<dim3(32, 64), 256, 0, stream>>>(ybuf, w1T, b1, nullptr, (void*)hbuf, M, MLPD, HID);
  // out = d_out + h @ w2 + b2
  k_gemm<2><<<dim3(8, 64), 256, 0, stream>>>(hbuf, w2T, b2, out, (void*)out, M, HID, MLPD);
}

// Round 8
// 399.294 us; speedup vs baseline: 1.5634x; 1.1056x over previous
//
#include <hip/hip_runtime.h>
#include <math.h>

typedef __attribute__((ext_vector_type(8))) __bf16 bf16x8;
typedef __attribute__((ext_vector_type(4))) float f32x4;

#define NBATCH 8
#define SEQ    1024
#define NHEAD  16
#define DHEAD  64
#define HID    1024
#define MLPD   4096

static __device__ __forceinline__ unsigned short f2bf(float f) {
  unsigned int u = __float_as_uint(f);
  u += 0x7fffu + ((u >> 16) & 1u);
  return (unsigned short)(u >> 16);
}

// async global->LDS, 16B per lane; LDS dest is wave-uniform base + lane*16
static __device__ __forceinline__ void gload_lds16(const unsigned short* g,
                                                   unsigned short* l) {
  __builtin_amdgcn_global_load_lds(
      (const __attribute__((address_space(1))) unsigned int*)g,
      (__attribute__((address_space(3))) unsigned int*)l, 16, 0, 0);
}

// exact tanh-gelu via __expf: tanh(z) = sign(z)*(1-e^{-2|z|})/(1+e^{-2|z|})
static __device__ __forceinline__ float gelu_fast(float v) {
  const float z = 0.7978845608028654f * (v + 0.044715f * v * v * v);
  const float e = __expf(-2.0f * fabsf(z));
  float th = (1.0f - e) / (1.0f + e);
  th = copysignf(th, z);
  return 0.5f * v * (1.0f + th);
}

// ---------- transpose: in f32 (R x C) -> out bf16 (C x R) ----------
__global__ __launch_bounds__(256) void k_transpose(const float* __restrict__ in,
                                                   unsigned short* __restrict__ out,
                                                   int R, int C) {
  __shared__ float t[32][33];
  const int tx = threadIdx.x & 31, ty = threadIdx.x >> 5;  // 32 x 8
  const int c0 = blockIdx.x * 32, r0 = blockIdx.y * 32;
#pragma unroll
  for (int j = 0; j < 4; ++j)
    t[ty + j * 8][tx] = in[(size_t)(r0 + ty + j * 8) * C + c0 + tx];
  __syncthreads();
#pragma unroll
  for (int j = 0; j < 4; ++j)
    out[(size_t)(c0 + ty + j * 8) * R + r0 + tx] = f2bf(t[tx][ty + j * 8]);
}

// ---------- pack q/k/v biases into one 3072 vector ----------
__global__ void k_pack_bias(const float* __restrict__ bq, const float* __restrict__ bk,
                            const float* __restrict__ bv, float* __restrict__ o) {
  int i = blockIdx.x * 256 + threadIdx.x;
  if (i < 3 * HID) {
    float v = (i < HID) ? bq[i] : (i < 2 * HID ? bk[i - HID] : bv[i - 2 * HID]);
    o[i] = v;
  }
}

// ---------- layernorm: f32 row (1024) -> bf16 row ----------
__global__ __launch_bounds__(256) void k_ln(const float* __restrict__ x,
                                            const float* __restrict__ gw,
                                            const float* __restrict__ bw,
                                            unsigned short* __restrict__ y) {
  __shared__ float red[2][4];
  const int row = blockIdx.x;
  const int tid = threadIdx.x;
  const float4 v = ((const float4*)(x + (size_t)row * HID))[tid];
  float sum = v.x + v.y + v.z + v.w;
  float sq  = v.x * v.x + v.y * v.y + v.z * v.z + v.w * v.w;
#pragma unroll
  for (int off = 32; off >= 1; off >>= 1) {
    sum += __shfl_xor(sum, off);
    sq  += __shfl_xor(sq, off);
  }
  if ((tid & 63) == 0) { red[0][tid >> 6] = sum; red[1][tid >> 6] = sq; }
  __syncthreads();
  sum = red[0][0] + red[0][1] + red[0][2] + red[0][3];
  sq  = red[1][0] + red[1][1] + red[1][2] + red[1][3];
  const float mu  = sum * (1.0f / HID);
  const float var = sq * (1.0f / HID) - mu * mu;
  const float rs  = rsqrtf(var + 1e-5f);
  const float4 g4 = ((const float4*)gw)[tid];
  const float4 b4 = ((const float4*)bw)[tid];
  ushort4 ov;
  ov.x = f2bf((v.x - mu) * rs * g4.x + b4.x);
  ov.y = f2bf((v.y - mu) * rs * g4.y + b4.y);
  ov.z = f2bf((v.z - mu) * rs * g4.z + b4.z);
  ov.w = f2bf((v.w - mu) * rs * g4.w + b4.w);
  ((ushort4*)(y + (size_t)row * HID))[tid] = ov;
}

// ---------- NT GEMM, 8-phase 256xBN template ----------
// C(MxN) = A(MxK) * BT(NxK)^T. 8 waves (512 thr), tile 256 x BN, BK=64.
// Per-wave output: 128 x (BN/4). LDS XOR-swizzled [row][128B] (byte^=(row&7)<<4),
// staged via global_load_lds with pre-swizzled per-lane SOURCE (linear dest).
// Schedule per K-tile: vmcnt(0)[loads issued one tile ago] + barrier; issue next
// tile's DMA; 4 phases of {ds_read A-frags; barrier; lgkmcnt(0); setprio(1);
// MFMA cluster; setprio(0); barrier}.
template <int EPI, int BN>
__global__ __launch_bounds__(512, 2) void k_gemm(const unsigned short* __restrict__ A,
                                                 const unsigned short* __restrict__ BT,
                                                 const float* __restrict__ bias,
                                                 const float* __restrict__ res,
                                                 void* __restrict__ Cout,
                                                 int M, int N, int K) {
  constexpr int ASZ = 256 * 64;        // ushorts per A buffer (256 rows x 64 elems)
  constexpr int BSZ = BN * 64;         // ushorts per B buffer
  constexpr int NF  = BN / 64;         // n-frags per wave (4 or 2)
  constexpr int NCW = BN / 4;          // per-wave n-width (64 or 32)
  constexpr int BCALLS = BN / 64;      // staging calls for B (rows/64)
  __shared__ unsigned short sh[2 * ASZ + 2 * BSZ];

  const int tid  = threadIdx.x;
  const int lane = tid & 63;
  const int w    = tid >> 6;           // 0..7
  const int wr   = w >> 2, wc = w & 3; // 2 x 4 wave grid
  const int l15  = lane & 15, g = lane >> 4;
  const int m0 = blockIdx.y * 256, n0 = blockIdx.x * BN;

  f32x4 acc[8][NF] = {};

  // ---- staging addresses (pre-swizzled source, linear LDS dest) ----
  // call c covers tile rows [c*64, c*64+64); wave w rows +w*8; lane: +(lane>>3)
  const int srow  = w * 8 + (lane >> 3);                       // row within call block
  const int scolb = ((lane & 7) * 16) ^ (((lane >> 3) & 7) << 4);  // pre-swizzled byte col
  const unsigned short* pA = A  + (size_t)(m0 + srow) * K + (scolb >> 1);
  const unsigned short* pB = BT + (size_t)(n0 + srow) * K + (scolb >> 1);
  unsigned short* shB = sh + 2 * ASZ;

#define STAGE(buf, kk)                                                          \
  do {                                                                          \
    _Pragma("unroll") for (int c = 0; c < 4; ++c)                               \
      gload_lds16(pA + (size_t)c * 64 * K + (kk),                               \
                  sh + (buf) * ASZ + (c * 64 + w * 8) * 64);                    \
    _Pragma("unroll") for (int c = 0; c < BCALLS; ++c)                          \
      gload_lds16(pB + (size_t)c * 64 * K + (kk),                               \
                  shB + (buf) * BSZ + (c * 64 + w * 8) * 64);                   \
  } while (0)

  // ---- fragment read offsets (swizzled) ----
  const int fmask = (l15 & 7) << 4;                 // byte XOR mask (row&7)<<4
  const int bo0 = ((0 * 64) + g * 16) ^ fmask;      // ksub 0 byte-in-row
  const int bo1 = ((1 * 64) + g * 16) ^ fmask;      // ksub 1
  const int aRowBase = wr * 128 + l15;              // + m*16
  const int bRowBase = wc * NCW + l15;              // + n*16

  const int NT = K >> 6;  // K-tiles of 64

  STAGE(0, 0);
  int buf = 0;
  for (int t = 0; t < NT; ++t) {
    // loads for tile t were issued one full tile ago -> near-zero stall
    asm volatile("s_waitcnt vmcnt(0)" ::: "memory");
    __builtin_amdgcn_sched_barrier(0);
    __builtin_amdgcn_s_barrier();     // everyone's DMA for tile t visible
    if (t + 1 < NT) STAGE(buf ^ 1, (t + 1) * 64);

    const unsigned short* shAb = sh + buf * ASZ;
    const unsigned short* shBb = shB + buf * BSZ;

    bf16x8 bfr[NF][2];
#pragma unroll
    for (int n = 0; n < NF; ++n) {
      const int br = (bRowBase + n * 16) * 64;
      bfr[n][0] = *(const bf16x8*)(shBb + br + (bo0 >> 1));
      bfr[n][1] = *(const bf16x8*)(shBb + br + (bo1 >> 1));
    }

#pragma unroll
    for (int p = 0; p < 4; ++p) {
      const int ar0 = (aRowBase + (2 * p) * 16) * 64;
      const int ar1 = (aRowBase + (2 * p + 1) * 16) * 64;
      const bf16x8 a00 = *(const bf16x8*)(shAb + ar0 + (bo0 >> 1));
      const bf16x8 a01 = *(const bf16x8*)(shAb + ar0 + (bo1 >> 1));
      const bf16x8 a10 = *(const bf16x8*)(shAb + ar1 + (bo0 >> 1));
      const bf16x8 a11 = *(const bf16x8*)(shAb + ar1 + (bo1 >> 1));
      __builtin_amdgcn_s_barrier();
      asm volatile("s_waitcnt lgkmcnt(0)" ::: "memory");
      __builtin_amdgcn_sched_barrier(0);
      __builtin_amdgcn_s_setprio(1);
#pragma unroll
      for (int n = 0; n < NF; ++n) {
        acc[2 * p][n]     = __builtin_amdgcn_mfma_f32_16x16x32_bf16(a00, bfr[n][0], acc[2 * p][n], 0, 0, 0);
        acc[2 * p][n]     = __builtin_amdgcn_mfma_f32_16x16x32_bf16(a01, bfr[n][1], acc[2 * p][n], 0, 0, 0);
        acc[2 * p + 1][n] = __builtin_amdgcn_mfma_f32_16x16x32_bf16(a10, bfr[n][0], acc[2 * p + 1][n], 0, 0, 0);
        acc[2 * p + 1][n] = __builtin_amdgcn_mfma_f32_16x16x32_bf16(a11, bfr[n][1], acc[2 * p + 1][n], 0, 0, 0);
      }
      __builtin_amdgcn_s_setprio(0);
      __builtin_amdgcn_s_barrier();
    }
    buf ^= 1;
  }
#undef STAGE

  if constexpr (EPI == 2) {
    // f32 out + residual: 16-lane x 4B contiguous = full 64B lines
#pragma unroll
    for (int m = 0; m < 8; ++m) {
#pragma unroll
      for (int n = 0; n < NF; ++n) {
        const int col = n0 + wc * NCW + n * 16 + l15;
        const float bc = bias[col];
#pragma unroll
        for (int r = 0; r < 4; ++r) {
          const int row = m0 + wr * 128 + m * 16 + g * 4 + r;
          const size_t idx = (size_t)row * N + col;
          ((float*)Cout)[idx] = acc[m][n][r] + bc + res[idx];
        }
      }
    }
  } else {
    // bf16 out via per-wave LDS tile (128 x NCW) -> wide coalesced stores
    unsigned short* ep = sh + w * (128 * NCW);
#pragma unroll
    for (int m = 0; m < 8; ++m) {
#pragma unroll
      for (int n = 0; n < NF; ++n) {
        const float bc = bias[n0 + wc * NCW + n * 16 + l15];
#pragma unroll
        for (int r = 0; r < 4; ++r) {
          float v = acc[m][n][r] + bc;
          if constexpr (EPI == 1) v = gelu_fast(v);
          ep[(m * 16 + g * 4 + r) * NCW + n * 16 + l15] = f2bf(v);
        }
      }
    }
    // 128*NCW ushorts = 16*NCW uint4; 64 lanes -> NCW/4 iters
    constexpr int CPR = NCW / 8;   // 16B chunks per row (8 or 4)
#pragma unroll
    for (int j = 0; j < NCW / 4; ++j) {
      const int t = lane + j * 64;
      const int row = t / CPR, colb = (t % CPR) * 8;
      const uint4 vv = *(const uint4*)(ep + row * NCW + colb);
      unsigned short* outp = (unsigned short*)Cout +
          (size_t)(m0 + wr * 128 + row) * N + n0 + wc * NCW + colb;
      *(uint4*)outp = vv;
    }
  }
}

// ---------- V transpose: qkv (M x 3072) V-columns -> vT [nh][64][1024] bf16 ----------
__global__ __launch_bounds__(256) void k_vt(const unsigned short* __restrict__ qkv,
                                            unsigned short* __restrict__ vT) {
  __shared__ unsigned short t[64][72];
  const int nh = blockIdx.y;           // nb*16 + h
  const int nb = nh >> 4, h = nh & 15;
  const int l0 = blockIdx.x * 64;
  const int tx = threadIdx.x & 7;      // 8 chunks of 8 d-elems
  const int ty = threadIdx.x >> 3;     // 32 l-rows
  const unsigned short* src = qkv + (size_t)(nb * SEQ + l0) * 3072 + 2048 + h * DHEAD;
#pragma unroll
  for (int j = 0; j < 2; ++j)
    *(uint4*)(&t[ty + j * 32][tx * 8]) =
        *(const uint4*)(&src[(size_t)(ty + j * 32) * 3072 + tx * 8]);
  __syncthreads();
  unsigned short* dst = vT + (size_t)nh * DHEAD * SEQ + l0;
#pragma unroll
  for (int j = 0; j < 2; ++j) {
    const int d = ty + j * 32;
    ushort4 a, b;
    a.x = t[tx * 8 + 0][d]; a.y = t[tx * 8 + 1][d];
    a.z = t[tx * 8 + 2][d]; a.w = t[tx * 8 + 3][d];
    b.x = t[tx * 8 + 4][d]; b.y = t[tx * 8 + 5][d];
    b.z = t[tx * 8 + 6][d]; b.w = t[tx * 8 + 7][d];
    *(ushort4*)(&dst[(size_t)d * SEQ + tx * 8])     = a;
    *(ushort4*)(&dst[(size_t)d * SEQ + tx * 8 + 4]) = b;
  }
}

// ---------- flash attention, LDS-staged K/V, swapped QK^T ----------
#define SOFTMAX_GROUP(S, gq)                                                       \
  {                                                                                \
    float mx = -INFINITY;                                                          \
    _Pragma("unroll") for (int c = 0; c < 4; ++c)                                  \
      _Pragma("unroll") for (int r = 0; r < 4; ++r)                                \
        mx = fmaxf(mx, S[c][r]);                                                   \
    mx = fmaxf(mx, __shfl_xor(mx, 16));                                            \
    mx = fmaxf(mx, __shfl_xor(mx, 32));                                            \
    const float mnew = fmaxf(m_run[gq], mx);                                       \
    const float sc = __expf(0.125f * (m_run[gq] - mnew));                          \
    m_run[gq] = mnew;                                                              \
    float ts = 0.0f;                                                               \
    _Pragma("unroll") for (int c = 0; c < 4; ++c) {                                \
      const float p0 = __expf(0.125f * (S[c][0] - mnew));                          \
      const float p1 = __expf(0.125f * (S[c][1] - mnew));                          \
      const float p2 = __expf(0.125f * (S[c][2] - mnew));                          \
      const float p3 = __expf(0.125f * (S[c][3] - mnew));                          \
      ts += (p0 + p1) + (p2 + p3);                                                 \
      const unsigned int lo = (unsigned int)f2bf(p0) | ((unsigned int)f2bf(p1) << 16); \
      const unsigned int hi = (unsigned int)f2bf(p2) | ((unsigned int)f2bf(p3) << 16); \
      *(uint2*)(&P_lds[w][((gq) * 16 + l15) * 72 + c * 16 + g * 4]) = make_uint2(lo, hi); \
    }                                                                              \
    ts += __shfl_xor(ts, 16);                                                      \
    ts += __shfl_xor(ts, 32);                                                      \
    s_run[gq] = s_run[gq] * sc + ts;                                               \
    const float scr0 = __shfl(sc, g * 4 + 0), scr1 = __shfl(sc, g * 4 + 1);        \
    const float scr2 = __shfl(sc, g * 4 + 2), scr3 = __shfl(sc, g * 4 + 3);        \
    _Pragma("unroll") for (int dt = 0; dt < 4; ++dt) {                             \
      o[gq][dt][0] *= scr0; o[gq][dt][1] *= scr1;                                  \
      o[gq][dt][2] *= scr2; o[gq][dt][3] *= scr3;                                  \
    }                                                                              \
  }

__global__ __launch_bounds__(256, 4) void k_attn(const unsigned short* __restrict__ qkv,
                                                 const unsigned short* __restrict__ vT,
                                                 unsigned short* __restrict__ outp) {
  __shared__ unsigned short Ks[64 * 64];           // 8 KB, swizzled
  __shared__ unsigned short Vs[64 * 64];           // 8 KB, swizzled
  __shared__ unsigned short P_lds[4][32 * 72];     // 18 KB, per-wave P
  const int tid  = threadIdx.x;
  const int lane = tid & 63;
  const int w    = tid >> 6;
  const int l15  = lane & 15, g = lane >> 4;
  const int nh = blockIdx.y;
  const int nb = nh >> 4, h = nh & 15;
  const int q0 = blockIdx.x * 128 + w * 32;        // wave's 32 q-rows
  const size_t RS = 3 * HID;

  const unsigned short* Qp = qkv + (size_t)(nb * SEQ + q0) * RS + h * DHEAD;
  const unsigned short* Kg = qkv + (size_t)(nb * SEQ) * RS + HID + h * DHEAD;
  const unsigned short* Vg = vT + (size_t)nh * DHEAD * SEQ;

  const int L0 = tid * 32, L1 = L0 + 16;
  const int kr0 = L0 >> 7, kc0 = (L0 & 127) ^ ((kr0 & 7) << 4);
  const int kr1 = L1 >> 7, kc1 = (L1 & 127) ^ ((kr1 & 7) << 4);

  bf16x8 aq[2][2];
#pragma unroll
  for (int gq = 0; gq < 2; ++gq)
#pragma unroll
    for (int t = 0; t < 2; ++t)
      aq[gq][t] = *(const bf16x8*)(&Qp[(size_t)(gq * 16 + l15) * RS + t * 32 + g * 8]);

  f32x4 o[2][4] = {};
  float m_run[2] = {-INFINITY, -INFINITY};
  float s_run[2] = {0.0f, 0.0f};

  uint4 rk0, rk1, rv0, rv1;
  rk0 = *(const uint4*)(Kg + (size_t)kr0 * RS + (kc0 >> 1));
  rk1 = *(const uint4*)(Kg + (size_t)kr1 * RS + (kc1 >> 1));
  rv0 = *(const uint4*)(Vg + (size_t)kr0 * SEQ + (kc0 >> 1));
  rv1 = *(const uint4*)(Vg + (size_t)kr1 * SEQ + (kc1 >> 1));
  *(uint4*)(&Ks[tid * 16])     = rk0;
  *(uint4*)(&Ks[tid * 16 + 8]) = rk1;
  *(uint4*)(&Vs[tid * 16])     = rv0;
  *(uint4*)(&Vs[tid * 16 + 8]) = rv1;
  __syncthreads();

  const int sw = (l15 & 7) << 4;  // byte-swizzle for fragment reads

  for (int t16 = 0; t16 < 16; ++t16) {
    if (t16 < 15) {
      const int kb = (t16 + 1) * 64;
      rk0 = *(const uint4*)(Kg + (size_t)(kb + kr0) * RS + (kc0 >> 1));
      rk1 = *(const uint4*)(Kg + (size_t)(kb + kr1) * RS + (kc1 >> 1));
      rv0 = *(const uint4*)(Vg + (size_t)kr0 * SEQ + kb + (kc0 >> 1));
      rv1 = *(const uint4*)(Vg + (size_t)kr1 * SEQ + kb + (kc1 >> 1));
    }

    f32x4 S0[4], S1[4];
#pragma unroll
    for (int c = 0; c < 4; ++c) {
      const int krow = c * 16 + l15;
      const bf16x8 k0 = *(const bf16x8*)(&Ks[krow * 64 + ((( 0 + g * 16) ^ sw) >> 1)]);
      const bf16x8 k1 = *(const bf16x8*)(&Ks[krow * 64 + (((64 + g * 16) ^ sw) >> 1)]);
      f32x4 a = {};
      a = __builtin_amdgcn_mfma_f32_16x16x32_bf16(k0, aq[0][0], a, 0, 0, 0);
      a = __builtin_amdgcn_mfma_f32_16x16x32_bf16(k1, aq[0][1], a, 0, 0, 0);
      S0[c] = a;
      f32x4 b = {};
      b = __builtin_amdgcn_mfma_f32_16x16x32_bf16(k0, aq[1][0], b, 0, 0, 0);
      b = __builtin_amdgcn_mfma_f32_16x16x32_bf16(k1, aq[1][1], b, 0, 0, 0);
      S1[c] = b;
    }

    SOFTMAX_GROUP(S0, 0)
    SOFTMAX_GROUP(S1, 1)

    bf16x8 pa[2][2];
#pragma unroll
    for (int gq = 0; gq < 2; ++gq)
#pragma unroll
      for (int th = 0; th < 2; ++th)
        pa[gq][th] = *(const bf16x8*)(&P_lds[w][(gq * 16 + l15) * 72 + th * 32 + g * 8]);
#pragma unroll
    for (int dt = 0; dt < 4; ++dt) {
      const int vrow = dt * 16 + l15;
      const bf16x8 v0 = *(const bf16x8*)(&Vs[vrow * 64 + ((( 0 + g * 16) ^ sw) >> 1)]);
      const bf16x8 v1 = *(const bf16x8*)(&Vs[vrow * 64 + (((64 + g * 16) ^ sw) >> 1)]);
      o[0][dt] = __builtin_amdgcn_mfma_f32_16x16x32_bf16(pa[0][0], v0, o[0][dt], 0, 0, 0);
      o[0][dt] = __builtin_amdgcn_mfma_f32_16x16x32_bf16(pa[0][1], v1, o[0][dt], 0, 0, 0);
      o[1][dt] = __builtin_amdgcn_mfma_f32_16x16x32_bf16(pa[1][0], v0, o[1][dt], 0, 0, 0);
      o[1][dt] = __builtin_amdgcn_mfma_f32_16x16x32_bf16(pa[1][1], v1, o[1][dt], 0, 0, 0);
    }
    __syncthreads();
    if (t16 < 15) {
      *(uint4*)(&Ks[tid * 16])     = rk0;
      *(uint4*)(&Ks[tid * 16 + 8]) = rk1;
      *(uint4*)(&Vs[tid * 16])     = rv0;
      *(uint4*)(&Vs[tid * 16 + 8]) = rv1;
      __syncthreads();
    }
  }

#pragma unroll
  for (int gq = 0; gq < 2; ++gq) {
    float sr[4];
#pragma unroll
    for (int r = 0; r < 4; ++r) sr[r] = 1.0f / __shfl(s_run[gq], g * 4 + r);
#pragma unroll
    for (int dt = 0; dt < 4; ++dt)
#pragma unroll
      for (int r = 0; r < 4; ++r)
        outp[(size_t)(nb * SEQ + q0 + gq * 16 + g * 4 + r) * HID + h * DHEAD + dt * 16 + l15] =
            f2bf(o[gq][dt][r] * sr[r]);
  }
}

extern "C" void kernel_launch(void* const* d_in, const int* in_sizes, int n_in,
                              void* d_out, int out_size, void* d_ws, size_t ws_size,
                              hipStream_t stream) {
  const float* x    = (const float*)d_in[0];
  const float* ln0g = (const float*)d_in[1];
  const float* ln0b = (const float*)d_in[2];
  const float* wq   = (const float*)d_in[3];
  const float* bq   = (const float*)d_in[4];
  const float* wk   = (const float*)d_in[5];
  const float* bk   = (const float*)d_in[6];
  const float* wv   = (const float*)d_in[7];
  const float* bv   = (const float*)d_in[8];
  const float* wo   = (const float*)d_in[9];
  const float* bo   = (const float*)d_in[10];
  const float* ln1g = (const float*)d_in[11];
  const float* ln1b = (const float*)d_in[12];
  const float* w1   = (const float*)d_in[13];
  const float* b1   = (const float*)d_in[14];
  const float* w2   = (const float*)d_in[15];
  const float* b2   = (const float*)d_in[16];
  float* out = (float*)d_out;

  char* ws = (char*)d_ws;
  unsigned short* qkvT = (unsigned short*)(ws + 0);          // 3072x1024 bf16   (6 MB)
  unsigned short* woT  = (unsigned short*)(ws + 6291456);    // 1024x1024 bf16   (2 MB)
  unsigned short* w1T  = (unsigned short*)(ws + 8388608);    // 4096x1024 bf16   (8 MB)
  unsigned short* w2T  = (unsigned short*)(ws + 16777216);   // 1024x4096 bf16   (8 MB)
  float*          bqkv = (float*)(ws + 25165824);            // 3072 f32
  unsigned short* ybuf = (unsigned short*)(ws + 25178112);   // 8192x1024 bf16   (16 MB)
  unsigned short* qkv  = (unsigned short*)(ws + 41955328);   // 8192x3072 bf16   (48 MB)
  unsigned short* att  = (unsigned short*)(ws + 92286976);   // 8192x1024 bf16   (16 MB)
  unsigned short* hbuf = qkv;   // 8192x4096 bf16 (64 MB) overlays qkv+att (both dead)
  unsigned short* vT   = ybuf;  // 128x64x1024 bf16 (16 MB) overlays ybuf (dead between QKV-GEMM and LN1)

  const int M = NBATCH * SEQ;  // 8192

  // weight prep
  k_transpose<<<dim3(32, 32),  256, 0, stream>>>(wq, qkvT,                        HID,  HID);
  k_transpose<<<dim3(32, 32),  256, 0, stream>>>(wk, qkvT + (size_t)1024 * HID,   HID,  HID);
  k_transpose<<<dim3(32, 32),  256, 0, stream>>>(wv, qkvT + (size_t)2048 * HID,   HID,  HID);
  k_transpose<<<dim3(32, 32),  256, 0, stream>>>(wo, woT,                         HID,  HID);
  k_transpose<<<dim3(128, 32), 256, 0, stream>>>(w1, w1T,                         HID,  MLPD);
  k_transpose<<<dim3(32, 128), 256, 0, stream>>>(w2, w2T,                         MLPD, HID);
  k_pack_bias<<<dim3(12), 256, 0, stream>>>(bq, bk, bv, bqkv);

  // LN0 -> y
  k_ln<<<dim3(M), 256, 0, stream>>>(x, ln0g, ln0b, ybuf);
  // QKV: qkv = y @ [wq|wk|wv] + b   (M x 3072)   BN=128 -> 24x32 = 768 blocks
  k_gemm<0, 128><<<dim3(24, 32), 512, 0, stream>>>(ybuf, qkvT, bqkv, nullptr, (void*)qkv, M, 3 * HID, HID);
  // V^T materialization (ybuf is dead now)
  k_vt<<<dim3(16, 128), 256, 0, stream>>>(qkv, vT);
  // attention
  k_attn<<<dim3(8, 128), 256, 0, stream>>>(qkv, vT, att);
  // x1 = x + att @ wo + bo  -> d_out (f32)        BN=128 -> 8x32 = 256 blocks
  k_gemm<2, 128><<<dim3(8, 32), 512, 0, stream>>>(att, woT, bo, x, (void*)out, M, HID, HID);
  // LN1 -> y
  k_ln<<<dim3(M), 256, 0, stream>>>(out, ln1g, ln1b, ybuf);
  // h = gelu(y @ w1 + b1)  (M x 4096)             BN=256 -> 16x32 = 512 blocks
  k_gemm<1, 256><<<dim3(16, 32), 512, 0, stream>>>(ybuf, w1T, b1, nullptr, (void*)hbuf, M, MLPD, HID);
  // out = d_out + h @ w2 + b2                     BN=128 -> 8x32 = 256 blocks
  k_gemm<2, 128><<<dim3(8, 32), 512, 0, stream>>>(hbuf, w2T, b2, out, (void*)out, M, HID, MLPD);
}

// Round 9
// 396.926 us; speedup vs baseline: 1.5728x; 1.0060x over previous
//
#include <hip/hip_runtime.h>
#include <math.h>

typedef __attribute__((ext_vector_type(8))) __bf16 bf16x8;
typedef __attribute__((ext_vector_type(4))) float f32x4;

#define NBATCH 8
#define SEQ    1024
#define NHEAD  16
#define DHEAD  64
#define HID    1024
#define MLPD   4096

static __device__ __forceinline__ unsigned short f2bf(float f) {
  unsigned int u = __float_as_uint(f);
  u += 0x7fffu + ((u >> 16) & 1u);
  return (unsigned short)(u >> 16);
}

// async global->LDS, 16B per lane; LDS dest is wave-uniform base + lane*16
static __device__ __forceinline__ void gload_lds16(const unsigned short* g,
                                                   unsigned short* l) {
  __builtin_amdgcn_global_load_lds(
      (const __attribute__((address_space(1))) unsigned int*)g,
      (__attribute__((address_space(3))) unsigned int*)l, 16, 0, 0);
}

// exact tanh-gelu via __expf: tanh(z) = sign(z)*(1-e^{-2|z|})/(1+e^{-2|z|})
static __device__ __forceinline__ float gelu_fast(float v) {
  const float z = 0.7978845608028654f * (v + 0.044715f * v * v * v);
  const float e = __expf(-2.0f * fabsf(z));
  float th = (1.0f - e) / (1.0f + e);
  th = copysignf(th, z);
  return 0.5f * v * (1.0f + th);
}

#define MFMA16(a, b, c) __builtin_amdgcn_mfma_f32_16x16x32_bf16(a, b, c, 0, 0, 0)

// ---------- transpose: in f32 (R x C) -> out bf16 (C x R) ----------
__global__ __launch_bounds__(256) void k_transpose(const float* __restrict__ in,
                                                   unsigned short* __restrict__ out,
                                                   int R, int C) {
  __shared__ float t[32][33];
  const int tx = threadIdx.x & 31, ty = threadIdx.x >> 5;  // 32 x 8
  const int c0 = blockIdx.x * 32, r0 = blockIdx.y * 32;
#pragma unroll
  for (int j = 0; j < 4; ++j)
    t[ty + j * 8][tx] = in[(size_t)(r0 + ty + j * 8) * C + c0 + tx];
  __syncthreads();
#pragma unroll
  for (int j = 0; j < 4; ++j)
    out[(size_t)(c0 + ty + j * 8) * R + r0 + tx] = f2bf(t[tx][ty + j * 8]);
}

// ---------- pack q/k/v biases into one 3072 vector ----------
__global__ void k_pack_bias(const float* __restrict__ bq, const float* __restrict__ bk,
                            const float* __restrict__ bv, float* __restrict__ o) {
  int i = blockIdx.x * 256 + threadIdx.x;
  if (i < 3 * HID) {
    float v = (i < HID) ? bq[i] : (i < 2 * HID ? bk[i - HID] : bv[i - 2 * HID]);
    o[i] = v;
  }
}

// ---------- layernorm: f32 row (1024) -> bf16 row ----------
__global__ __launch_bounds__(256) void k_ln(const float* __restrict__ x,
                                            const float* __restrict__ gw,
                                            const float* __restrict__ bw,
                                            unsigned short* __restrict__ y) {
  __shared__ float red[2][4];
  const int row = blockIdx.x;
  const int tid = threadIdx.x;
  const float4 v = ((const float4*)(x + (size_t)row * HID))[tid];
  float sum = v.x + v.y + v.z + v.w;
  float sq  = v.x * v.x + v.y * v.y + v.z * v.z + v.w * v.w;
#pragma unroll
  for (int off = 32; off >= 1; off >>= 1) {
    sum += __shfl_xor(sum, off);
    sq  += __shfl_xor(sq, off);
  }
  if ((tid & 63) == 0) { red[0][tid >> 6] = sum; red[1][tid >> 6] = sq; }
  __syncthreads();
  sum = red[0][0] + red[0][1] + red[0][2] + red[0][3];
  sq  = red[1][0] + red[1][1] + red[1][2] + red[1][3];
  const float mu  = sum * (1.0f / HID);
  const float var = sq * (1.0f / HID) - mu * mu;
  const float rs  = rsqrtf(var + 1e-5f);
  const float4 g4 = ((const float4*)gw)[tid];
  const float4 b4 = ((const float4*)bw)[tid];
  ushort4 ov;
  ov.x = f2bf((v.x - mu) * rs * g4.x + b4.x);
  ov.y = f2bf((v.y - mu) * rs * g4.y + b4.y);
  ov.z = f2bf((v.z - mu) * rs * g4.z + b4.z);
  ov.w = f2bf((v.w - mu) * rs * g4.w + b4.w);
  ((ushort4*)(y + (size_t)row * HID))[tid] = ov;
}

// ---------- NT GEMM, 8-phase 256xBN template with counted vmcnt (T3+T4) ----------
// C(MxN) = A(MxK) * BT(NxK)^T. 8 waves (512 thr), tile 256 x BN, BK=64.
// Staging of tile t+1 is spread 2 calls/phase in order [B...][A0,A2][A1,A3];
// gates: phase0 vmcnt(2), phase2 vmcnt(4) (0 on last tile) -- newest loads stay
// in flight across barriers (m218: counted-vs-drain0 is the whole 8-phase gain).
template <int EPI, int BN>
__global__ __launch_bounds__(512, 2) void k_gemm(const unsigned short* __restrict__ A,
                                                 const unsigned short* __restrict__ BT,
                                                 const float* __restrict__ bias,
                                                 const float* __restrict__ res,
                                                 void* __restrict__ Cout,
                                                 int M, int N, int K) {
  constexpr int ASZ = 256 * 64;        // ushorts per A buffer
  constexpr int BSZ = BN * 64;         // ushorts per B buffer
  constexpr int NF  = BN / 64;         // n-frags per wave (4 or 2)
  constexpr int NCW = BN / 4;          // per-wave n-width (64 or 32)
  __shared__ unsigned short sh[2 * ASZ + 2 * BSZ];

  const int tid  = threadIdx.x;
  const int lane = tid & 63;
  const int w    = tid >> 6;           // 0..7
  const int wr   = w >> 2, wc = w & 3; // 2 x 4 wave grid
  const int l15  = lane & 15, g = lane >> 4;
  const int m0 = blockIdx.y * 256, n0 = blockIdx.x * BN;

  f32x4 acc[8][NF] = {};

  // staging: call c covers 64 rows; wave w rows +w*8; lane +(lane>>3); source
  // column pre-swizzled (XOR involution), LDS dest linear.
  const int srow  = w * 8 + (lane >> 3);
  const int scolb = ((lane & 7) * 16) ^ (((lane >> 3) & 7) << 4);
  const unsigned short* pA = A  + (size_t)(m0 + srow) * K + (scolb >> 1);
  const unsigned short* pB = BT + (size_t)(n0 + srow) * K + (scolb >> 1);
  unsigned short* shB = sh + 2 * ASZ;

#define SB(i, bufv, kk) gload_lds16(pB + (size_t)(i) * 64 * K + (kk), \
                                    shB + (bufv) * BSZ + ((i) * 64 + w * 8) * 64);
#define SA(i, bufv, kk) gload_lds16(pA + (size_t)(i) * 64 * K + (kk), \
                                    sh + (bufv) * ASZ + ((i) * 64 + w * 8) * 64);

  // fragment read offsets (swizzled)
  const int fmask = (l15 & 7) << 4;
  const int bo0 = ((0 * 64) + g * 16) ^ fmask;
  const int bo1 = ((1 * 64) + g * 16) ^ fmask;
  const int aRowBase = wr * 128 + l15;
  const int bRowBase = wc * NCW + l15;

  const int NT = K >> 6;

  // prologue: stage tile 0 in canonical order (B..., A0, A2, A1, A3)
  SB(0, 0, 0) SB(1, 0, 0)
  if constexpr (BN == 256) { SB(2, 0, 0) SB(3, 0, 0) }
  SA(0, 0, 0) SA(2, 0, 0) SA(1, 0, 0) SA(3, 0, 0)

#define PHASE_TAIL(p, STAGECODE)                                                 \
  {                                                                              \
    const int ar0 = (aRowBase + (2 * (p)) * 16) * 64;                            \
    const int ar1 = (aRowBase + (2 * (p) + 1) * 16) * 64;                        \
    const bf16x8 a00 = *(const bf16x8*)(shAb + ar0 + (bo0 >> 1));                \
    const bf16x8 a01 = *(const bf16x8*)(shAb + ar0 + (bo1 >> 1));                \
    const bf16x8 a10 = *(const bf16x8*)(shAb + ar1 + (bo0 >> 1));                \
    const bf16x8 a11 = *(const bf16x8*)(shAb + ar1 + (bo1 >> 1));                \
    STAGECODE                                                                    \
    __builtin_amdgcn_s_barrier();                                                \
    asm volatile("s_waitcnt lgkmcnt(0)" ::: "memory");                           \
    __builtin_amdgcn_sched_barrier(0);                                           \
    __builtin_amdgcn_s_setprio(1);                                               \
    _Pragma("unroll") for (int n = 0; n < NF; ++n) {                             \
      acc[2 * (p)][n]     = MFMA16(a00, bfr[n][0], acc[2 * (p)][n]);             \
      acc[2 * (p)][n]     = MFMA16(a01, bfr[n][1], acc[2 * (p)][n]);             \
      acc[2 * (p) + 1][n] = MFMA16(a10, bfr[n][0], acc[2 * (p) + 1][n]);         \
      acc[2 * (p) + 1][n] = MFMA16(a11, bfr[n][1], acc[2 * (p) + 1][n]);         \
    }                                                                            \
    __builtin_amdgcn_s_setprio(0);                                               \
  }

  int buf = 0;
  for (int t = 0; t < NT; ++t) {
    const unsigned short* shAb = sh + buf * ASZ;
    const unsigned short* shBb = shB + buf * BSZ;
    const int bufn = buf ^ 1;
    const int nxt = (t + 1) * 64;
    const bool more = (t + 1 < NT);
    bf16x8 bfr[NF][2];

    // ---- phase 0: gate vmcnt(2) (A1,A3 of this tile may still fly) ----
    asm volatile("s_waitcnt vmcnt(2)" ::: "memory");
    __builtin_amdgcn_sched_barrier(0);
    __builtin_amdgcn_s_barrier();
#pragma unroll
    for (int n = 0; n < NF; ++n) {
      const int br = (bRowBase + n * 16) * 64;
      bfr[n][0] = *(const bf16x8*)(shBb + br + (bo0 >> 1));
      bfr[n][1] = *(const bf16x8*)(shBb + br + (bo1 >> 1));
    }
    PHASE_TAIL(0, if (more) { SB(0, bufn, nxt) SB(1, bufn, nxt) })

    // ---- phase 1 ----
    PHASE_TAIL(1, if (more) {
      if constexpr (BN == 256) { SB(2, bufn, nxt) SB(3, bufn, nxt) }
      else                     { SA(0, bufn, nxt) SA(2, bufn, nxt) }
    })

    // ---- phase 2: gate vmcnt(4) (4 newest = t+1's stages so far) ----
    if (more) asm volatile("s_waitcnt vmcnt(4)" ::: "memory");
    else      asm volatile("s_waitcnt vmcnt(0)" ::: "memory");
    __builtin_amdgcn_sched_barrier(0);
    __builtin_amdgcn_s_barrier();
    PHASE_TAIL(2, if (more) {
      if constexpr (BN == 256) { SA(0, bufn, nxt) SA(2, bufn, nxt) }
      else                     { SA(1, bufn, nxt) SA(3, bufn, nxt) }
    })

    // ---- phase 3 ----
    PHASE_TAIL(3, if (more) {
      if constexpr (BN == 256) { SA(1, bufn, nxt) SA(3, bufn, nxt) }
    })

    buf ^= 1;
  }
#undef PHASE_TAIL
#undef SB
#undef SA

  if constexpr (EPI == 2) {
    // f32 out + residual: 16-lane x 4B contiguous = full 64B lines
#pragma unroll
    for (int m = 0; m < 8; ++m) {
#pragma unroll
      for (int n = 0; n < NF; ++n) {
        const int col = n0 + wc * NCW + n * 16 + l15;
        const float bc = bias[col];
#pragma unroll
        for (int r = 0; r < 4; ++r) {
          const int row = m0 + wr * 128 + m * 16 + g * 4 + r;
          const size_t idx = (size_t)row * N + col;
          ((float*)Cout)[idx] = acc[m][n][r] + bc + res[idx];
        }
      }
    }
  } else {
    // bf16 out via per-wave LDS tile (128 x NCW) -> wide coalesced stores
    __builtin_amdgcn_s_barrier();
    unsigned short* ep = sh + w * (128 * NCW);
#pragma unroll
    for (int m = 0; m < 8; ++m) {
#pragma unroll
      for (int n = 0; n < NF; ++n) {
        const float bc = bias[n0 + wc * NCW + n * 16 + l15];
#pragma unroll
        for (int r = 0; r < 4; ++r) {
          float v = acc[m][n][r] + bc;
          if constexpr (EPI == 1) v = gelu_fast(v);
          ep[(m * 16 + g * 4 + r) * NCW + n * 16 + l15] = f2bf(v);
        }
      }
    }
    constexpr int CPR = NCW / 8;   // 16B chunks per row
#pragma unroll
    for (int j = 0; j < NCW / 4; ++j) {
      const int t = lane + j * 64;
      const int row = t / CPR, colb = (t % CPR) * 8;
      const uint4 vv = *(const uint4*)(ep + row * NCW + colb);
      unsigned short* outp = (unsigned short*)Cout +
          (size_t)(m0 + wr * 128 + row) * N + n0 + wc * NCW + colb;
      *(uint4*)outp = vv;
    }
  }
}

// ---------- V transpose: qkv (M x 3072) V-columns -> vT [nh][64][1024] bf16 ----------
__global__ __launch_bounds__(256) void k_vt(const unsigned short* __restrict__ qkv,
                                            unsigned short* __restrict__ vT) {
  __shared__ unsigned short t[64][72];
  const int nh = blockIdx.y;           // nb*16 + h
  const int nb = nh >> 4, h = nh & 15;
  const int l0 = blockIdx.x * 64;
  const int tx = threadIdx.x & 7;      // 8 chunks of 8 d-elems
  const int ty = threadIdx.x >> 3;     // 32 l-rows
  const unsigned short* src = qkv + (size_t)(nb * SEQ + l0) * 3072 + 2048 + h * DHEAD;
#pragma unroll
  for (int j = 0; j < 2; ++j)
    *(uint4*)(&t[ty + j * 32][tx * 8]) =
        *(const uint4*)(&src[(size_t)(ty + j * 32) * 3072 + tx * 8]);
  __syncthreads();
  unsigned short* dst = vT + (size_t)nh * DHEAD * SEQ + l0;
#pragma unroll
  for (int j = 0; j < 2; ++j) {
    const int d = ty + j * 32;
    ushort4 a, b;
    a.x = t[tx * 8 + 0][d]; a.y = t[tx * 8 + 1][d];
    a.z = t[tx * 8 + 2][d]; a.w = t[tx * 8 + 3][d];
    b.x = t[tx * 8 + 4][d]; b.y = t[tx * 8 + 5][d];
    b.z = t[tx * 8 + 6][d]; b.w = t[tx * 8 + 7][d];
    *(ushort4*)(&dst[(size_t)d * SEQ + tx * 8])     = a;
    *(ushort4*)(&dst[(size_t)d * SEQ + tx * 8 + 4]) = b;
  }
}

// ---------- flash attention, LDS-staged K/V, swapped QK^T ----------
#define SOFTMAX_GROUP(S, gq)                                                       \
  {                                                                                \
    float mx = -INFINITY;                                                          \
    _Pragma("unroll") for (int c = 0; c < 4; ++c)                                  \
      _Pragma("unroll") for (int r = 0; r < 4; ++r)                                \
        mx = fmaxf(mx, S[c][r]);                                                   \
    mx = fmaxf(mx, __shfl_xor(mx, 16));                                            \
    mx = fmaxf(mx, __shfl_xor(mx, 32));                                            \
    const float mnew = fmaxf(m_run[gq], mx);                                       \
    const float sc = __expf(0.125f * (m_run[gq] - mnew));                          \
    m_run[gq] = mnew;                                                              \
    float ts = 0.0f;                                                               \
    _Pragma("unroll") for (int c = 0; c < 4; ++c) {                                \
      const float p0 = __expf(0.125f * (S[c][0] - mnew));                          \
      const float p1 = __expf(0.125f * (S[c][1] - mnew));                          \
      const float p2 = __expf(0.125f * (S[c][2] - mnew));                          \
      const float p3 = __expf(0.125f * (S[c][3] - mnew));                          \
      ts += (p0 + p1) + (p2 + p3);                                                 \
      const unsigned int lo = (unsigned int)f2bf(p0) | ((unsigned int)f2bf(p1) << 16); \
      const unsigned int hi = (unsigned int)f2bf(p2) | ((unsigned int)f2bf(p3) << 16); \
      *(uint2*)(&P_lds[w][((gq) * 16 + l15) * 72 + c * 16 + g * 4]) = make_uint2(lo, hi); \
    }                                                                              \
    ts += __shfl_xor(ts, 16);                                                      \
    ts += __shfl_xor(ts, 32);                                                      \
    s_run[gq] = s_run[gq] * sc + ts;                                               \
    const float scr0 = __shfl(sc, g * 4 + 0), scr1 = __shfl(sc, g * 4 + 1);        \
    const float scr2 = __shfl(sc, g * 4 + 2), scr3 = __shfl(sc, g * 4 + 3);        \
    _Pragma("unroll") for (int dt = 0; dt < 4; ++dt) {                             \
      o[gq][dt][0] *= scr0; o[gq][dt][1] *= scr1;                                  \
      o[gq][dt][2] *= scr2; o[gq][dt][3] *= scr3;                                  \
    }                                                                              \
  }

__global__ __launch_bounds__(256, 4) void k_attn(const unsigned short* __restrict__ qkv,
                                                 const unsigned short* __restrict__ vT,
                                                 unsigned short* __restrict__ outp) {
  __shared__ unsigned short Ks[64 * 64];           // 8 KB, swizzled
  __shared__ unsigned short Vs[64 * 64];           // 8 KB, swizzled
  __shared__ unsigned short P_lds[4][32 * 72];     // 18 KB, per-wave P
  const int tid  = threadIdx.x;
  const int lane = tid & 63;
  const int w    = tid >> 6;
  const int l15  = lane & 15, g = lane >> 4;
  const int nh = blockIdx.y;
  const int nb = nh >> 4, h = nh & 15;
  const int q0 = blockIdx.x * 128 + w * 32;        // wave's 32 q-rows
  const size_t RS = 3 * HID;

  const unsigned short* Qp = qkv + (size_t)(nb * SEQ + q0) * RS + h * DHEAD;
  const unsigned short* Kg = qkv + (size_t)(nb * SEQ) * RS + HID + h * DHEAD;
  const unsigned short* Vg = vT + (size_t)nh * DHEAD * SEQ;

  const int L0 = tid * 32, L1 = L0 + 16;
  const int kr0 = L0 >> 7, kc0 = (L0 & 127) ^ ((kr0 & 7) << 4);
  const int kr1 = L1 >> 7, kc1 = (L1 & 127) ^ ((kr1 & 7) << 4);

  bf16x8 aq[2][2];
#pragma unroll
  for (int gq = 0; gq < 2; ++gq)
#pragma unroll
    for (int t = 0; t < 2; ++t)
      aq[gq][t] = *(const bf16x8*)(&Qp[(size_t)(gq * 16 + l15) * RS + t * 32 + g * 8]);

  f32x4 o[2][4] = {};
  float m_run[2] = {-INFINITY, -INFINITY};
  float s_run[2] = {0.0f, 0.0f};

  uint4 rk0, rk1, rv0, rv1;
  rk0 = *(const uint4*)(Kg + (size_t)kr0 * RS + (kc0 >> 1));
  rk1 = *(const uint4*)(Kg + (size_t)kr1 * RS + (kc1 >> 1));
  rv0 = *(const uint4*)(Vg + (size_t)kr0 * SEQ + (kc0 >> 1));
  rv1 = *(const uint4*)(Vg + (size_t)kr1 * SEQ + (kc1 >> 1));
  *(uint4*)(&Ks[tid * 16])     = rk0;
  *(uint4*)(&Ks[tid * 16 + 8]) = rk1;
  *(uint4*)(&Vs[tid * 16])     = rv0;
  *(uint4*)(&Vs[tid * 16 + 8]) = rv1;
  __syncthreads();

  const int sw = (l15 & 7) << 4;  // byte-swizzle for fragment reads

  for (int t16 = 0; t16 < 16; ++t16) {
    if (t16 < 15) {
      const int kb = (t16 + 1) * 64;
      rk0 = *(const uint4*)(Kg + (size_t)(kb + kr0) * RS + (kc0 >> 1));
      rk1 = *(const uint4*)(Kg + (size_t)(kb + kr1) * RS + (kc1 >> 1));
      rv0 = *(const uint4*)(Vg + (size_t)kr0 * SEQ + kb + (kc0 >> 1));
      rv1 = *(const uint4*)(Vg + (size_t)kr1 * SEQ + kb + (kc1 >> 1));
    }

    f32x4 S0[4], S1[4];
#pragma unroll
    for (int c = 0; c < 4; ++c) {
      const int krow = c * 16 + l15;
      const bf16x8 k0 = *(const bf16x8*)(&Ks[krow * 64 + ((( 0 + g * 16) ^ sw) >> 1)]);
      const bf16x8 k1 = *(const bf16x8*)(&Ks[krow * 64 + (((64 + g * 16) ^ sw) >> 1)]);
      f32x4 a = {};
      a = MFMA16(k0, aq[0][0], a);
      a = MFMA16(k1, aq[0][1], a);
      S0[c] = a;
      f32x4 b = {};
      b = MFMA16(k0, aq[1][0], b);
      b = MFMA16(k1, aq[1][1], b);
      S1[c] = b;
    }

    SOFTMAX_GROUP(S0, 0)
    SOFTMAX_GROUP(S1, 1)

    bf16x8 pa[2][2];
#pragma unroll
    for (int gq = 0; gq < 2; ++gq)
#pragma unroll
      for (int th = 0; th < 2; ++th)
        pa[gq][th] = *(const bf16x8*)(&P_lds[w][(gq * 16 + l15) * 72 + th * 32 + g * 8]);
#pragma unroll
    for (int dt = 0; dt < 4; ++dt) {
      const int vrow = dt * 16 + l15;
      const bf16x8 v0 = *(const bf16x8*)(&Vs[vrow * 64 + ((( 0 + g * 16) ^ sw) >> 1)]);
      const bf16x8 v1 = *(const bf16x8*)(&Vs[vrow * 64 + (((64 + g * 16) ^ sw) >> 1)]);
      o[0][dt] = MFMA16(pa[0][0], v0, o[0][dt]);
      o[0][dt] = MFMA16(pa[0][1], v1, o[0][dt]);
      o[1][dt] = MFMA16(pa[1][0], v0, o[1][dt]);
      o[1][dt] = MFMA16(pa[1][1], v1, o[1][dt]);
    }
    __syncthreads();
    if (t16 < 15) {
      *(uint4*)(&Ks[tid * 16])     = rk0;
      *(uint4*)(&Ks[tid * 16 + 8]) = rk1;
      *(uint4*)(&Vs[tid * 16])     = rv0;
      *(uint4*)(&Vs[tid * 16 + 8]) = rv1;
      __syncthreads();
    }
  }

#pragma unroll
  for (int gq = 0; gq < 2; ++gq) {
    float sr[4];
#pragma unroll
    for (int r = 0; r < 4; ++r) sr[r] = 1.0f / __shfl(s_run[gq], g * 4 + r);
#pragma unroll
    for (int dt = 0; dt < 4; ++dt)
#pragma unroll
      for (int r = 0; r < 4; ++r)
        outp[(size_t)(nb * SEQ + q0 + gq * 16 + g * 4 + r) * HID + h * DHEAD + dt * 16 + l15] =
            f2bf(o[gq][dt][r] * sr[r]);
  }
}

extern "C" void kernel_launch(void* const* d_in, const int* in_sizes, int n_in,
                              void* d_out, int out_size, void* d_ws, size_t ws_size,
                              hipStream_t stream) {
  const float* x    = (const float*)d_in[0];
  const float* ln0g = (const float*)d_in[1];
  const float* ln0b = (const float*)d_in[2];
  const float* wq   = (const float*)d_in[3];
  const float* bq   = (const float*)d_in[4];
  const float* wk   = (const float*)d_in[5];
  const float* bk   = (const float*)d_in[6];
  const float* wv   = (const float*)d_in[7];
  const float* bv   = (const float*)d_in[8];
  const float* wo   = (const float*)d_in[9];
  const float* bo   = (const float*)d_in[10];
  const float* ln1g = (const float*)d_in[11];
  const float* ln1b = (const float*)d_in[12];
  const float* w1   = (const float*)d_in[13];
  const float* b1   = (const float*)d_in[14];
  const float* w2   = (const float*)d_in[15];
  const float* b2   = (const float*)d_in[16];
  float* out = (float*)d_out;

  char* ws = (char*)d_ws;
  unsigned short* qkvT = (unsigned short*)(ws + 0);          // 3072x1024 bf16   (6 MB)
  unsigned short* woT  = (unsigned short*)(ws + 6291456);    // 1024x1024 bf16   (2 MB)
  unsigned short* w1T  = (unsigned short*)(ws + 8388608);    // 4096x1024 bf16   (8 MB)
  unsigned short* w2T  = (unsigned short*)(ws + 16777216);   // 1024x4096 bf16   (8 MB)
  float*          bqkv = (float*)(ws + 25165824);            // 3072 f32
  unsigned short* ybuf = (unsigned short*)(ws + 25178112);   // 8192x1024 bf16   (16 MB)
  unsigned short* qkv  = (unsigned short*)(ws + 41955328);   // 8192x3072 bf16   (48 MB)
  unsigned short* att  = (unsigned short*)(ws + 92286976);   // 8192x1024 bf16   (16 MB)
  unsigned short* hbuf = qkv;   // 8192x4096 bf16 (64 MB) overlays qkv+att (both dead)
  unsigned short* vT   = ybuf;  // 128x64x1024 bf16 (16 MB) overlays ybuf (dead between QKV-GEMM and LN1)

  const int M = NBATCH * SEQ;  // 8192

  // weight prep
  k_transpose<<<dim3(32, 32),  256, 0, stream>>>(wq, qkvT,                        HID,  HID);
  k_transpose<<<dim3(32, 32),  256, 0, stream>>>(wk, qkvT + (size_t)1024 * HID,   HID,  HID);
  k_transpose<<<dim3(32, 32),  256, 0, stream>>>(wv, qkvT + (size_t)2048 * HID,   HID,  HID);
  k_transpose<<<dim3(32, 32),  256, 0, stream>>>(wo, woT,                         HID,  HID);
  k_transpose<<<dim3(128, 32), 256, 0, stream>>>(w1, w1T,                         HID,  MLPD);
  k_transpose<<<dim3(32, 128), 256, 0, stream>>>(w2, w2T,                         MLPD, HID);
  k_pack_bias<<<dim3(12), 256, 0, stream>>>(bq, bk, bv, bqkv);

  // LN0 -> y
  k_ln<<<dim3(M), 256, 0, stream>>>(x, ln0g, ln0b, ybuf);
  // QKV: qkv = y @ [wq|wk|wv] + b   (M x 3072)   BN=128 -> 24x32 blocks
  k_gemm<0, 128><<<dim3(24, 32), 512, 0, stream>>>(ybuf, qkvT, bqkv, nullptr, (void*)qkv, M, 3 * HID, HID);
  // V^T materialization (ybuf is dead now)
  k_vt<<<dim3(16, 128), 256, 0, stream>>>(qkv, vT);
  // attention
  k_attn<<<dim3(8, 128), 256, 0, stream>>>(qkv, vT, att);
  // x1 = x + att @ wo + bo  -> d_out (f32)        BN=128 -> 8x32 blocks
  k_gemm<2, 128><<<dim3(8, 32), 512, 0, stream>>>(att, woT, bo, x, (void*)out, M, HID, HID);
  // LN1 -> y
  k_ln<<<dim3(M), 256, 0, stream>>>(out, ln1g, ln1b, ybuf);
  // h = gelu(y @ w1 + b1)  (M x 4096)             BN=256 -> 16x32 blocks
  k_gemm<1, 256><<<dim3(16, 32), 512, 0, stream>>>(ybuf, w1T, b1, nullptr, (void*)hbuf, M, MLPD, HID);
  // out = d_out + h @ w2 + b2                     BN=128 -> 8x32 blocks
  k_gemm<2, 128><<<dim3(8, 32), 512, 0, stream>>>(hbuf, w2T, b2, out, (void*)out, M, HID, MLPD);
}

// Round 10
// 376.817 us; speedup vs baseline: 1.6567x; 1.0534x over previous
//
#include <hip/hip_runtime.h>
#include <math.h>

typedef __attribute__((ext_vector_type(8))) __bf16 bf16x8;
typedef __attribute__((ext_vector_type(4))) float f32x4;

#define NBATCH 8
#define SEQ    1024
#define NHEAD  16
#define DHEAD  64
#define HID    1024
#define MLPD   4096

static __device__ __forceinline__ unsigned short f2bf(float f) {
  unsigned int u = __float_as_uint(f);
  u += 0x7fffu + ((u >> 16) & 1u);
  return (unsigned short)(u >> 16);
}

// async global->LDS, 16B per lane; LDS dest is wave-uniform base + lane*16
static __device__ __forceinline__ void gload_lds16(const unsigned short* g,
                                                   unsigned short* l) {
  __builtin_amdgcn_global_load_lds(
      (const __attribute__((address_space(1))) unsigned int*)g,
      (__attribute__((address_space(3))) unsigned int*)l, 16, 0, 0);
}

// exact tanh-gelu via __expf: tanh(z) = sign(z)*(1-e^{-2|z|})/(1+e^{-2|z|})
static __device__ __forceinline__ float gelu_fast(float v) {
  const float z = 0.7978845608028654f * (v + 0.044715f * v * v * v);
  const float e = __expf(-2.0f * fabsf(z));
  float th = (1.0f - e) / (1.0f + e);
  th = copysignf(th, z);
  return 0.5f * v * (1.0f + th);
}

#define MFMA16(a, b, c) __builtin_amdgcn_mfma_f32_16x16x32_bf16(a, b, c, 0, 0, 0)

// ---------- transpose: in f32 (R x C) -> out bf16 (C x R) ----------
__global__ __launch_bounds__(256) void k_transpose(const float* __restrict__ in,
                                                   unsigned short* __restrict__ out,
                                                   int R, int C) {
  __shared__ float t[32][33];
  const int tx = threadIdx.x & 31, ty = threadIdx.x >> 5;  // 32 x 8
  const int c0 = blockIdx.x * 32, r0 = blockIdx.y * 32;
#pragma unroll
  for (int j = 0; j < 4; ++j)
    t[ty + j * 8][tx] = in[(size_t)(r0 + ty + j * 8) * C + c0 + tx];
  __syncthreads();
#pragma unroll
  for (int j = 0; j < 4; ++j)
    out[(size_t)(c0 + ty + j * 8) * R + r0 + tx] = f2bf(t[tx][ty + j * 8]);
}

// ---------- pack q/k/v biases into one 3072 vector ----------
__global__ void k_pack_bias(const float* __restrict__ bq, const float* __restrict__ bk,
                            const float* __restrict__ bv, float* __restrict__ o) {
  int i = blockIdx.x * 256 + threadIdx.x;
  if (i < 3 * HID) {
    float v = (i < HID) ? bq[i] : (i < 2 * HID ? bk[i - HID] : bv[i - 2 * HID]);
    o[i] = v;
  }
}

// ---------- layernorm: f32 row (1024) -> bf16 row ----------
__global__ __launch_bounds__(256) void k_ln(const float* __restrict__ x,
                                            const float* __restrict__ gw,
                                            const float* __restrict__ bw,
                                            unsigned short* __restrict__ y) {
  __shared__ float red[2][4];
  const int row = blockIdx.x;
  const int tid = threadIdx.x;
  const float4 v = ((const float4*)(x + (size_t)row * HID))[tid];
  float sum = v.x + v.y + v.z + v.w;
  float sq  = v.x * v.x + v.y * v.y + v.z * v.z + v.w * v.w;
#pragma unroll
  for (int off = 32; off >= 1; off >>= 1) {
    sum += __shfl_xor(sum, off);
    sq  += __shfl_xor(sq, off);
  }
  if ((tid & 63) == 0) { red[0][tid >> 6] = sum; red[1][tid >> 6] = sq; }
  __syncthreads();
  sum = red[0][0] + red[0][1] + red[0][2] + red[0][3];
  sq  = red[1][0] + red[1][1] + red[1][2] + red[1][3];
  const float mu  = sum * (1.0f / HID);
  const float var = sq * (1.0f / HID) - mu * mu;
  const float rs  = rsqrtf(var + 1e-5f);
  const float4 g4 = ((const float4*)gw)[tid];
  const float4 b4 = ((const float4*)bw)[tid];
  ushort4 ov;
  ov.x = f2bf((v.x - mu) * rs * g4.x + b4.x);
  ov.y = f2bf((v.y - mu) * rs * g4.y + b4.y);
  ov.z = f2bf((v.z - mu) * rs * g4.z + b4.z);
  ov.w = f2bf((v.w - mu) * rs * g4.w + b4.w);
  ((ushort4*)(y + (size_t)row * HID))[tid] = ov;
}

// ---------- NT GEMM, 256xBN tile, free-running tile body ----------
// C(MxN) = A(MxK) * BT(NxK)^T. 8 waves (512 thr), tile 256 x BN, BK=64.
// Per K-tile: ONE gate {vmcnt(0); s_barrier} (exact: only tile t's DMA is
// outstanding there), issue all of t+1's DMA, pre-issue ALL 24 fragment
// ds_reads (pinned before MFMAs), then 4 MFMA clusters with NO intra-tile
// barriers -- waves de-phase so LDS returns and MFMA bursts overlap across
// the 2 waves/SIMD (m114 mechanism). LDS XOR-swizzled (byte^=(row&7)<<4).
template <int EPI, int BN>
__global__ __launch_bounds__(512, 2) void k_gemm(const unsigned short* __restrict__ A,
                                                 const unsigned short* __restrict__ BT,
                                                 const float* __restrict__ bias,
                                                 const float* __restrict__ res,
                                                 void* __restrict__ Cout,
                                                 int M, int N, int K) {
  constexpr int ASZ = 256 * 64;        // ushorts per A buffer
  constexpr int BSZ = BN * 64;         // ushorts per B buffer
  constexpr int NF  = BN / 64;         // n-frags per wave (4 or 2)
  constexpr int NCW = BN / 4;          // per-wave n-width (64 or 32)
  __shared__ unsigned short sh[2 * ASZ + 2 * BSZ];

  const int tid  = threadIdx.x;
  const int lane = tid & 63;
  const int w    = tid >> 6;           // 0..7
  const int wr   = w >> 2, wc = w & 3; // 2 x 4 wave grid
  const int l15  = lane & 15, g = lane >> 4;

  // XCD-chunked swizzle: dispatch d -> work lid (d&7)*(nwg/8)+(d>>3), so one
  // XCD's blocks are CONSECUTIVE lids (share A-panels in its L2).
  const int gx = gridDim.x;
  const int nwg = gx * gridDim.y;
  int lid = blockIdx.y * gx + blockIdx.x;
  lid = (lid & 7) * (nwg >> 3) + (lid >> 3);
  const int m0 = (lid / gx) * 256, n0 = (lid % gx) * BN;

  f32x4 acc[8][NF] = {};

  // staging: call c covers 64 rows; wave w rows +w*8; lane +(lane>>3); source
  // column pre-swizzled (XOR involution), LDS dest linear.
  const int srow  = w * 8 + (lane >> 3);
  const int scolb = ((lane & 7) * 16) ^ (((lane >> 3) & 7) << 4);
  const unsigned short* pA = A  + (size_t)(m0 + srow) * K + (scolb >> 1);
  const unsigned short* pB = BT + (size_t)(n0 + srow) * K + (scolb >> 1);
  unsigned short* shB = sh + 2 * ASZ;

#define STAGE(buf_, kk)                                                     \
  do {                                                                      \
    _Pragma("unroll") for (int c = 0; c < 4; ++c)                           \
      gload_lds16(pA + (size_t)c * 64 * K + (kk),                           \
                  sh + (buf_) * ASZ + (c * 64 + w * 8) * 64);               \
    _Pragma("unroll") for (int c = 0; c < BN / 64; ++c)                     \
      gload_lds16(pB + (size_t)c * 64 * K + (kk),                           \
                  shB + (buf_) * BSZ + (c * 64 + w * 8) * 64);              \
  } while (0)

  // fragment read offsets (swizzled)
  const int fmask = (l15 & 7) << 4;
  const int bo0 = ((0 * 64) + g * 16) ^ fmask;
  const int bo1 = ((1 * 64) + g * 16) ^ fmask;
  const int aRowBase = wr * 128 + l15;
  const int bRowBase = wc * NCW + l15;

  const int NT = K >> 6;

  STAGE(0, 0);
  int buf = 0;
  for (int t = 0; t < NT; ++t) {
    const unsigned short* shAb = sh + buf * ASZ;
    const unsigned short* shBb = shB + buf * BSZ;

    // gate: per-wave drain of its own DMA, then block rendezvous -> all of
    // tile t's LDS writes complete; all waves done reading buf^1 (tile t-1).
    asm volatile("s_waitcnt vmcnt(0)" ::: "memory");
    __builtin_amdgcn_sched_barrier(0);
    __builtin_amdgcn_s_barrier();
    if (t + 1 < NT) STAGE(buf ^ 1, (t + 1) * 64);

    // pre-issue ALL fragment reads for tile t
    bf16x8 bfr[NF][2];
#pragma unroll
    for (int n = 0; n < NF; ++n) {
      const int br = (bRowBase + n * 16) * 64;
      bfr[n][0] = *(const bf16x8*)(shBb + br + (bo0 >> 1));
      bfr[n][1] = *(const bf16x8*)(shBb + br + (bo1 >> 1));
    }
    bf16x8 afr[8][2];
#pragma unroll
    for (int m = 0; m < 8; ++m) {
      const int ar = (aRowBase + m * 16) * 64;
      afr[m][0] = *(const bf16x8*)(shAb + ar + (bo0 >> 1));
      afr[m][1] = *(const bf16x8*)(shAb + ar + (bo1 >> 1));
    }
    __builtin_amdgcn_sched_barrier(0);  // loads stay above the MFMA section

    // 4 MFMA clusters, no barriers: compiler inserts counted lgkmcnt per use
#pragma unroll
    for (int p = 0; p < 4; ++p) {
      __builtin_amdgcn_s_setprio(1);
#pragma unroll
      for (int n = 0; n < NF; ++n) {
        acc[2 * p][n]     = MFMA16(afr[2 * p][0],     bfr[n][0], acc[2 * p][n]);
        acc[2 * p][n]     = MFMA16(afr[2 * p][1],     bfr[n][1], acc[2 * p][n]);
        acc[2 * p + 1][n] = MFMA16(afr[2 * p + 1][0], bfr[n][0], acc[2 * p + 1][n]);
        acc[2 * p + 1][n] = MFMA16(afr[2 * p + 1][1], bfr[n][1], acc[2 * p + 1][n]);
      }
      __builtin_amdgcn_s_setprio(0);
    }
    buf ^= 1;
  }
#undef STAGE

  if constexpr (EPI == 2) {
    // f32 out + residual: 16-lane x 4B contiguous = full 64B lines
#pragma unroll
    for (int m = 0; m < 8; ++m) {
#pragma unroll
      for (int n = 0; n < NF; ++n) {
        const int col = n0 + wc * NCW + n * 16 + l15;
        const float bc = bias[col];
#pragma unroll
        for (int r = 0; r < 4; ++r) {
          const int row = m0 + wr * 128 + m * 16 + g * 4 + r;
          const size_t idx = (size_t)row * N + col;
          ((float*)Cout)[idx] = acc[m][n][r] + bc + res[idx];
        }
      }
    }
  } else {
    // bf16 out via per-wave LDS tile (128 x NCW) -> wide coalesced stores
    __builtin_amdgcn_s_barrier();
    unsigned short* ep = sh + w * (128 * NCW);
#pragma unroll
    for (int m = 0; m < 8; ++m) {
#pragma unroll
      for (int n = 0; n < NF; ++n) {
        const float bc = bias[n0 + wc * NCW + n * 16 + l15];
#pragma unroll
        for (int r = 0; r < 4; ++r) {
          float v = acc[m][n][r] + bc;
          if constexpr (EPI == 1) v = gelu_fast(v);
          ep[(m * 16 + g * 4 + r) * NCW + n * 16 + l15] = f2bf(v);
        }
      }
    }
    constexpr int CPR = NCW / 8;   // 16B chunks per row
#pragma unroll
    for (int j = 0; j < NCW / 4; ++j) {
      const int t = lane + j * 64;
      const int row = t / CPR, colb = (t % CPR) * 8;
      const uint4 vv = *(const uint4*)(ep + row * NCW + colb);
      unsigned short* outp = (unsigned short*)Cout +
          (size_t)(m0 + wr * 128 + row) * N + n0 + wc * NCW + colb;
      *(uint4*)outp = vv;
    }
  }
}

// ---------- V transpose: qkv (M x 3072) V-columns -> vT [nh][64][1024] bf16 ----------
__global__ __launch_bounds__(256) void k_vt(const unsigned short* __restrict__ qkv,
                                            unsigned short* __restrict__ vT) {
  __shared__ unsigned short t[64][72];
  const int nh = blockIdx.y;           // nb*16 + h
  const int nb = nh >> 4, h = nh & 15;
  const int l0 = blockIdx.x * 64;
  const int tx = threadIdx.x & 7;      // 8 chunks of 8 d-elems
  const int ty = threadIdx.x >> 3;     // 32 l-rows
  const unsigned short* src = qkv + (size_t)(nb * SEQ + l0) * 3072 + 2048 + h * DHEAD;
#pragma unroll
  for (int j = 0; j < 2; ++j)
    *(uint4*)(&t[ty + j * 32][tx * 8]) =
        *(const uint4*)(&src[(size_t)(ty + j * 32) * 3072 + tx * 8]);
  __syncthreads();
  unsigned short* dst = vT + (size_t)nh * DHEAD * SEQ + l0;
#pragma unroll
  for (int j = 0; j < 2; ++j) {
    const int d = ty + j * 32;
    ushort4 a, b;
    a.x = t[tx * 8 + 0][d]; a.y = t[tx * 8 + 1][d];
    a.z = t[tx * 8 + 2][d]; a.w = t[tx * 8 + 3][d];
    b.x = t[tx * 8 + 4][d]; b.y = t[tx * 8 + 5][d];
    b.z = t[tx * 8 + 6][d]; b.w = t[tx * 8 + 7][d];
    *(ushort4*)(&dst[(size_t)d * SEQ + tx * 8])     = a;
    *(ushort4*)(&dst[(size_t)d * SEQ + tx * 8 + 4]) = b;
  }
}

// ---------- flash attention, LDS-staged K/V, swapped QK^T ----------
#define SOFTMAX_GROUP(S, gq)                                                       \
  {                                                                                \
    float mx = -INFINITY;                                                          \
    _Pragma("unroll") for (int c = 0; c < 4; ++c)                                  \
      _Pragma("unroll") for (int r = 0; r < 4; ++r)                                \
        mx = fmaxf(mx, S[c][r]);                                                   \
    mx = fmaxf(mx, __shfl_xor(mx, 16));                                            \
    mx = fmaxf(mx, __shfl_xor(mx, 32));                                            \
    const float mnew = fmaxf(m_run[gq], mx);                                       \
    const float sc = __expf(0.125f * (m_run[gq] - mnew));                          \
    m_run[gq] = mnew;                                                              \
    float ts = 0.0f;                                                               \
    _Pragma("unroll") for (int c = 0; c < 4; ++c) {                                \
      const float p0 = __expf(0.125f * (S[c][0] - mnew));                          \
      const float p1 = __expf(0.125f * (S[c][1] - mnew));                          \
      const float p2 = __expf(0.125f * (S[c][2] - mnew));                          \
      const float p3 = __expf(0.125f * (S[c][3] - mnew));                          \
      ts += (p0 + p1) + (p2 + p3);                                                 \
      const unsigned int lo = (unsigned int)f2bf(p0) | ((unsigned int)f2bf(p1) << 16); \
      const unsigned int hi = (unsigned int)f2bf(p2) | ((unsigned int)f2bf(p3) << 16); \
      *(uint2*)(&P_lds[w][((gq) * 16 + l15) * 72 + c * 16 + g * 4]) = make_uint2(lo, hi); \
    }                                                                              \
    ts += __shfl_xor(ts, 16);                                                      \
    ts += __shfl_xor(ts, 32);                                                      \
    s_run[gq] = s_run[gq] * sc + ts;                                               \
    const float scr0 = __shfl(sc, g * 4 + 0), scr1 = __shfl(sc, g * 4 + 1);        \
    const float scr2 = __shfl(sc, g * 4 + 2), scr3 = __shfl(sc, g * 4 + 3);        \
    _Pragma("unroll") for (int dt = 0; dt < 4; ++dt) {                             \
      o[gq][dt][0] *= scr0; o[gq][dt][1] *= scr1;                                  \
      o[gq][dt][2] *= scr2; o[gq][dt][3] *= scr3;                                  \
    }                                                                              \
  }

__global__ __launch_bounds__(256, 4) void k_attn(const unsigned short* __restrict__ qkv,
                                                 const unsigned short* __restrict__ vT,
                                                 unsigned short* __restrict__ outp) {
  __shared__ unsigned short Ks[64 * 64];           // 8 KB, swizzled
  __shared__ unsigned short Vs[64 * 64];           // 8 KB, swizzled
  __shared__ unsigned short P_lds[4][32 * 72];     // 18 KB, per-wave P
  const int tid  = threadIdx.x;
  const int lane = tid & 63;
  const int w    = tid >> 6;
  const int l15  = lane & 15, g = lane >> 4;
  const int nh = blockIdx.y;
  const int nb = nh >> 4, h = nh & 15;
  const int q0 = blockIdx.x * 128 + w * 32;        // wave's 32 q-rows
  const size_t RS = 3 * HID;

  const unsigned short* Qp = qkv + (size_t)(nb * SEQ + q0) * RS + h * DHEAD;
  const unsigned short* Kg = qkv + (size_t)(nb * SEQ) * RS + HID + h * DHEAD;
  const unsigned short* Vg = vT + (size_t)nh * DHEAD * SEQ;

  const int L0 = tid * 32, L1 = L0 + 16;
  const int kr0 = L0 >> 7, kc0 = (L0 & 127) ^ ((kr0 & 7) << 4);
  const int kr1 = L1 >> 7, kc1 = (L1 & 127) ^ ((kr1 & 7) << 4);

  bf16x8 aq[2][2];
#pragma unroll
  for (int gq = 0; gq < 2; ++gq)
#pragma unroll
    for (int t = 0; t < 2; ++t)
      aq[gq][t] = *(const bf16x8*)(&Qp[(size_t)(gq * 16 + l15) * RS + t * 32 + g * 8]);

  f32x4 o[2][4] = {};
  float m_run[2] = {-INFINITY, -INFINITY};
  float s_run[2] = {0.0f, 0.0f};

  uint4 rk0, rk1, rv0, rv1;
  rk0 = *(const uint4*)(Kg + (size_t)kr0 * RS + (kc0 >> 1));
  rk1 = *(const uint4*)(Kg + (size_t)kr1 * RS + (kc1 >> 1));
  rv0 = *(const uint4*)(Vg + (size_t)kr0 * SEQ + (kc0 >> 1));
  rv1 = *(const uint4*)(Vg + (size_t)kr1 * SEQ + (kc1 >> 1));
  *(uint4*)(&Ks[tid * 16])     = rk0;
  *(uint4*)(&Ks[tid * 16 + 8]) = rk1;
  *(uint4*)(&Vs[tid * 16])     = rv0;
  *(uint4*)(&Vs[tid * 16 + 8]) = rv1;
  __syncthreads();

  const int sw = (l15 & 7) << 4;  // byte-swizzle for fragment reads

  for (int t16 = 0; t16 < 16; ++t16) {
    if (t16 < 15) {
      const int kb = (t16 + 1) * 64;
      rk0 = *(const uint4*)(Kg + (size_t)(kb + kr0) * RS + (kc0 >> 1));
      rk1 = *(const uint4*)(Kg + (size_t)(kb + kr1) * RS + (kc1 >> 1));
      rv0 = *(const uint4*)(Vg + (size_t)kr0 * SEQ + kb + (kc0 >> 1));
      rv1 = *(const uint4*)(Vg + (size_t)kr1 * SEQ + kb + (kc1 >> 1));
    }

    f32x4 S0[4], S1[4];
#pragma unroll
    for (int c = 0; c < 4; ++c) {
      const int krow = c * 16 + l15;
      const bf16x8 k0 = *(const bf16x8*)(&Ks[krow * 64 + ((( 0 + g * 16) ^ sw) >> 1)]);
      const bf16x8 k1 = *(const bf16x8*)(&Ks[krow * 64 + (((64 + g * 16) ^ sw) >> 1)]);
      f32x4 a = {};
      a = MFMA16(k0, aq[0][0], a);
      a = MFMA16(k1, aq[0][1], a);
      S0[c] = a;
      f32x4 b = {};
      b = MFMA16(k0, aq[1][0], b);
      b = MFMA16(k1, aq[1][1], b);
      S1[c] = b;
    }

    SOFTMAX_GROUP(S0, 0)
    SOFTMAX_GROUP(S1, 1)

    bf16x8 pa[2][2];
#pragma unroll
    for (int gq = 0; gq < 2; ++gq)
#pragma unroll
      for (int th = 0; th < 2; ++th)
        pa[gq][th] = *(const bf16x8*)(&P_lds[w][(gq * 16 + l15) * 72 + th * 32 + g * 8]);
#pragma unroll
    for (int dt = 0; dt < 4; ++dt) {
      const int vrow = dt * 16 + l15;
      const bf16x8 v0 = *(const bf16x8*)(&Vs[vrow * 64 + ((( 0 + g * 16) ^ sw) >> 1)]);
      const bf16x8 v1 = *(const bf16x8*)(&Vs[vrow * 64 + (((64 + g * 16) ^ sw) >> 1)]);
      o[0][dt] = MFMA16(pa[0][0], v0, o[0][dt]);
      o[0][dt] = MFMA16(pa[0][1], v1, o[0][dt]);
      o[1][dt] = MFMA16(pa[1][0], v0, o[1][dt]);
      o[1][dt] = MFMA16(pa[1][1], v1, o[1][dt]);
    }
    __syncthreads();
    if (t16 < 15) {
      *(uint4*)(&Ks[tid * 16])     = rk0;
      *(uint4*)(&Ks[tid * 16 + 8]) = rk1;
      *(uint4*)(&Vs[tid * 16])     = rv0;
      *(uint4*)(&Vs[tid * 16 + 8]) = rv1;
      __syncthreads();
    }
  }

#pragma unroll
  for (int gq = 0; gq < 2; ++gq) {
    float sr[4];
#pragma unroll
    for (int r = 0; r < 4; ++r) sr[r] = 1.0f / __shfl(s_run[gq], g * 4 + r);
#pragma unroll
    for (int dt = 0; dt < 4; ++dt)
#pragma unroll
      for (int r = 0; r < 4; ++r)
        outp[(size_t)(nb * SEQ + q0 + gq * 16 + g * 4 + r) * HID + h * DHEAD + dt * 16 + l15] =
            f2bf(o[gq][dt][r] * sr[r]);
  }
}

extern "C" void kernel_launch(void* const* d_in, const int* in_sizes, int n_in,
                              void* d_out, int out_size, void* d_ws, size_t ws_size,
                              hipStream_t stream) {
  const float* x    = (const float*)d_in[0];
  const float* ln0g = (const float*)d_in[1];
  const float* ln0b = (const float*)d_in[2];
  const float* wq   = (const float*)d_in[3];
  const float* bq   = (const float*)d_in[4];
  const float* wk   = (const float*)d_in[5];
  const float* bk   = (const float*)d_in[6];
  const float* wv   = (const float*)d_in[7];
  const float* bv   = (const float*)d_in[8];
  const float* wo   = (const float*)d_in[9];
  const float* bo   = (const float*)d_in[10];
  const float* ln1g = (const float*)d_in[11];
  const float* ln1b = (const float*)d_in[12];
  const float* w1   = (const float*)d_in[13];
  const float* b1   = (const float*)d_in[14];
  const float* w2   = (const float*)d_in[15];
  const float* b2   = (const float*)d_in[16];
  float* out = (float*)d_out;

  char* ws = (char*)d_ws;
  unsigned short* qkvT = (unsigned short*)(ws + 0);          // 3072x1024 bf16   (6 MB)
  unsigned short* woT  = (unsigned short*)(ws + 6291456);    // 1024x1024 bf16   (2 MB)
  unsigned short* w1T  = (unsigned short*)(ws + 8388608);    // 4096x1024 bf16   (8 MB)
  unsigned short* w2T  = (unsigned short*)(ws + 16777216);   // 1024x4096 bf16   (8 MB)
  float*          bqkv = (float*)(ws + 25165824);            // 3072 f32
  unsigned short* ybuf = (unsigned short*)(ws + 25178112);   // 8192x1024 bf16   (16 MB)
  unsigned short* qkv  = (unsigned short*)(ws + 41955328);   // 8192x3072 bf16   (48 MB)
  unsigned short* att  = (unsigned short*)(ws + 92286976);   // 8192x1024 bf16   (16 MB)
  unsigned short* hbuf = qkv;   // 8192x4096 bf16 (64 MB) overlays qkv+att (both dead)
  unsigned short* vT   = ybuf;  // 128x64x1024 bf16 (16 MB) overlays ybuf (dead between QKV-GEMM and LN1)

  const int M = NBATCH * SEQ;  // 8192

  // weight prep
  k_transpose<<<dim3(32, 32),  256, 0, stream>>>(wq, qkvT,                        HID,  HID);
  k_transpose<<<dim3(32, 32),  256, 0, stream>>>(wk, qkvT + (size_t)1024 * HID,   HID,  HID);
  k_transpose<<<dim3(32, 32),  256, 0, stream>>>(wv, qkvT + (size_t)2048 * HID,   HID,  HID);
  k_transpose<<<dim3(32, 32),  256, 0, stream>>>(wo, woT,                         HID,  HID);
  k_transpose<<<dim3(128, 32), 256, 0, stream>>>(w1, w1T,                         HID,  MLPD);
  k_transpose<<<dim3(32, 128), 256, 0, stream>>>(w2, w2T,                         MLPD, HID);
  k_pack_bias<<<dim3(12), 256, 0, stream>>>(bq, bk, bv, bqkv);

  // LN0 -> y
  k_ln<<<dim3(M), 256, 0, stream>>>(x, ln0g, ln0b, ybuf);
  // QKV: qkv = y @ [wq|wk|wv] + b   (M x 3072)   BN=128 -> 24x32 blocks
  k_gemm<0, 128><<<dim3(24, 32), 512, 0, stream>>>(ybuf, qkvT, bqkv, nullptr, (void*)qkv, M, 3 * HID, HID);
  // V^T materialization (ybuf is dead now)
  k_vt<<<dim3(16, 128), 256, 0, stream>>>(qkv, vT);
  // attention
  k_attn<<<dim3(8, 128), 256, 0, stream>>>(qkv, vT, att);
  // x1 = x + att @ wo + bo  -> d_out (f32)        BN=128 -> 8x32 blocks
  k_gemm<2, 128><<<dim3(8, 32), 512, 0, stream>>>(att, woT, bo, x, (void*)out, M, HID, HID);
  // LN1 -> y
  k_ln<<<dim3(M), 256, 0, stream>>>(out, ln1g, ln1b, ybuf);
  // h = gelu(y @ w1 + b1)  (M x 4096)             BN=256 -> 16x32 blocks
  k_gemm<1, 256><<<dim3(16, 32), 512, 0, stream>>>(ybuf, w1T, b1, nullptr, (void*)hbuf, M, MLPD, HID);
  // out = d_out + h @ w2 + b2                     BN=128 -> 8x32 blocks
  k_gemm<2, 128><<<dim3(8, 32), 512, 0, stream>>>(hbuf, w2T, b2, out, (void*)out, M, HID, MLPD);
}